// Round 1
// baseline (5639.177 us; speedup 1.0000x reference)
//
#include <hip/hip_runtime.h>
#include <hip/hip_bf16.h>
#include <math.h>

// Problem constants (BigBird regressor, B=2, S=4096)
#define D_    768
#define H_    12
#define DH_   64
#define BLK_  64
#define L_    2
#define R_    3
#define B_    2
#define S_    4096
#define NB_   64          // S_/BLK_
#define M_    (B_*S_)     // 8192 tokens
#define FF_   (4*D_)      // 3072

// ---------------------------------------------------------------- helpers

__device__ inline float gelu_f(float x) {
    float x3 = x * x * x;
    return 0.5f * x * (1.f + tanhf(0.7978845608f * (x + 0.044715f * x3)));
}

// block of 256 threads; returns full sum in every thread
__device__ inline float block_reduce_sum(float v, float* red) {
#pragma unroll
    for (int o = 32; o > 0; o >>= 1) v += __shfl_xor(v, o, 64);
    int wv = threadIdx.x >> 6;
    if ((threadIdx.x & 63) == 0) red[wv] = v;
    __syncthreads();
    float tot = red[0] + red[1] + red[2] + red[3];
    __syncthreads();
    return tot;
}

// ---------------------------------------------------------------- embed+LN

__global__ __launch_bounds__(256) void embed_ln_kernel(
    const int* __restrict__ ids, const float* __restrict__ etok,
    const float* __restrict__ epos, const float* __restrict__ g,
    const float* __restrict__ bb, float* __restrict__ x)
{
    __shared__ float red[4];
    const int tok = blockIdx.x;
    const int s   = tok & (S_ - 1);
    const int id  = ids[tok];
    const int t   = threadIdx.x;
    float v[3];
    float sum = 0.f;
#pragma unroll
    for (int i = 0; i < 3; i++) {
        int d = t + i * 256;
        v[i] = etok[(size_t)id * D_ + d] + epos[(size_t)s * D_ + d];
        sum += v[i];
    }
    float mean = block_reduce_sum(sum, red) * (1.f / 768.f);
    float sq = 0.f;
#pragma unroll
    for (int i = 0; i < 3; i++) { float dd = v[i] - mean; sq += dd * dd; }
    float var = block_reduce_sum(sq, red) * (1.f / 768.f);
    float inv = rsqrtf(var + 1e-12f);
#pragma unroll
    for (int i = 0; i < 3; i++) {
        int d = t + i * 256;
        x[(size_t)tok * D_ + d] = (v[i] - mean) * inv * g[d] + bb[d];
    }
}

// ---------------------------------------------------------------- add + LN (in-place on x)

__global__ __launch_bounds__(256) void add_ln_kernel(
    float* __restrict__ x, const float* __restrict__ y,
    const float* __restrict__ g, const float* __restrict__ bb)
{
    __shared__ float red[4];
    const int tok = blockIdx.x;
    const int t   = threadIdx.x;
    float* xr = x + (size_t)tok * D_;
    const float* yr = y + (size_t)tok * D_;
    float v[3];
    float sum = 0.f;
#pragma unroll
    for (int i = 0; i < 3; i++) {
        int d = t + i * 256;
        v[i] = xr[d] + yr[d];
        sum += v[i];
    }
    float mean = block_reduce_sum(sum, red) * (1.f / 768.f);
    float sq = 0.f;
#pragma unroll
    for (int i = 0; i < 3; i++) { float dd = v[i] - mean; sq += dd * dd; }
    float var = block_reduce_sum(sq, red) * (1.f / 768.f);
    float inv = rsqrtf(var + 1e-12f);
#pragma unroll
    for (int i = 0; i < 3; i++) {
        int d = t + i * 256;
        xr[d] = (v[i] - mean) * inv * g[d] + bb[d];
    }
}

// ---------------------------------------------------------------- fp32 GEMM: C = A[M,K] @ W[K,N] + bias (+gelu)
// 128x128 tile, BK=16, 256 threads, 8x8 micro-tile

template <int ACT>
__global__ __launch_bounds__(256) void gemm_kernel(
    const float* __restrict__ A, const float* __restrict__ W,
    const float* __restrict__ bias, float* __restrict__ C,
    int Md, int N, int K)
{
    __shared__ float As[16][132];   // [k][m] transposed
    __shared__ float Bs[16][132];   // [k][n]
    const int t  = threadIdx.x;
    const int tx = t & 15, ty = t >> 4;
    const int row0 = blockIdx.y * 128, col0 = blockIdx.x * 128;
    float acc[8][8];
#pragma unroll
    for (int i = 0; i < 8; i++)
#pragma unroll
        for (int j = 0; j < 8; j++) acc[i][j] = 0.f;

    for (int k0 = 0; k0 < K; k0 += 16) {
#pragma unroll
        for (int i = 0; i < 2; i++) {           // A tile: 128x16
            int e = t + i * 256;
            int r = e >> 2;
            int c = (e & 3) << 2;
            float4 a4 = *(const float4*)(A + (size_t)(row0 + r) * K + (k0 + c));
            As[c + 0][r] = a4.x; As[c + 1][r] = a4.y;
            As[c + 2][r] = a4.z; As[c + 3][r] = a4.w;
        }
#pragma unroll
        for (int i = 0; i < 2; i++) {           // B tile: 16x128
            int e = (t + i * 256) * 4;
            int r = e >> 7;
            int c = e & 127;
            float4 b4 = *(const float4*)(W + (size_t)(k0 + r) * N + (col0 + c));
            *(float4*)&Bs[r][c] = b4;
        }
        __syncthreads();
#pragma unroll
        for (int kk = 0; kk < 16; kk++) {
            float4 a0 = *(const float4*)&As[kk][ty * 8];
            float4 a1 = *(const float4*)&As[kk][ty * 8 + 4];
            float4 b0 = *(const float4*)&Bs[kk][tx * 8];
            float4 b1 = *(const float4*)&Bs[kk][tx * 8 + 4];
            float av[8] = {a0.x, a0.y, a0.z, a0.w, a1.x, a1.y, a1.z, a1.w};
            float bv[8] = {b0.x, b0.y, b0.z, b0.w, b1.x, b1.y, b1.z, b1.w};
#pragma unroll
            for (int i = 0; i < 8; i++)
#pragma unroll
                for (int j = 0; j < 8; j++)
                    acc[i][j] = fmaf(av[i], bv[j], acc[i][j]);
        }
        __syncthreads();
    }
#pragma unroll
    for (int i = 0; i < 8; i++) {
        size_t r = row0 + ty * 8 + i;
#pragma unroll
        for (int j = 0; j < 8; j += 4) {
            int c = col0 + tx * 8 + j;
            float4 o;
            o.x = acc[i][j + 0] + bias[c + 0];
            o.y = acc[i][j + 1] + bias[c + 1];
            o.z = acc[i][j + 2] + bias[c + 2];
            o.w = acc[i][j + 3] + bias[c + 3];
            if (ACT == 1) { o.x = gelu_f(o.x); o.y = gelu_f(o.y); o.z = gelu_f(o.z); o.w = gelu_f(o.w); }
            *(float4*)(C + r * N + c) = o;
        }
    }
}

// ---------------------------------------------------------------- BigBird attention
// one workgroup per (query block, head, batch); flash-style online softmax.
// Query blocks 0 and NB_-1 attend to all keys; others to the 8 gathered blocks
// [0, i-1, i, i+1, NB_-1, r0, r1, r2] (duplicates kept, matching reference).

__global__ __launch_bounds__(256) void attn_kernel(
    const float* __restrict__ q, const float* __restrict__ k,
    const float* __restrict__ v, const int* __restrict__ rnd,
    float* __restrict__ ctx)
{
    __shared__ float qs[DH_][BLK_ + 4];   // [d][qr]  (transposed)
    __shared__ float ks[DH_][BLK_ + 4];   // [d][kc]  (transposed)
    __shared__ float vs[BLK_][DH_ + 4];   // [kc][dh]
    __shared__ float sc[BLK_][BLK_ + 4];  // [kc][qr] (transposed scores / P)
    __shared__ float m_s[BLK_], l_s[BLK_], al_s[BLK_];

    const int ib = blockIdx.x, h = blockIdx.y, b = blockIdx.z;
    const int t  = threadIdx.x;
    const int r4 = t >> 2, g4 = t & 3;    // load & softmax mapping
    const int qi = t >> 4, ki = t & 15;   // compute mapping (4q x 4k / 4q x 4dh)

    {   // load Q tile transposed (once)
        const float* qbase = q + ((size_t)(b * S_ + ib * BLK_)) * D_ + h * DH_;
#pragma unroll
        for (int c = 0; c < 16; c += 4) {
            float4 f = *(const float4*)(qbase + r4 * D_ + g4 * 16 + c);
            qs[g4 * 16 + c + 0][r4] = f.x; qs[g4 * 16 + c + 1][r4] = f.y;
            qs[g4 * 16 + c + 2][r4] = f.z; qs[g4 * 16 + c + 3][r4] = f.w;
        }
    }
    if (t < BLK_) { m_s[t] = -1e30f; l_s[t] = 0.f; }

    float ctxacc[4][4];
#pragma unroll
    for (int a = 0; a < 4; a++)
#pragma unroll
        for (int c = 0; c < 4; c++) ctxacc[a][c] = 0.f;

    const bool full = (ib == 0) || (ib == NB_ - 1);
    const int nkb = full ? NB_ : 8;
    int rb[3];
    if (!full) {
        const int* rp = rnd + ((size_t)(h * NB_ + ib)) * R_;
        rb[0] = rp[0]; rb[1] = rp[1]; rb[2] = rp[2];
    }

    for (int kbi = 0; kbi < nkb; kbi++) {
        int kb;
        if (full) kb = kbi;
        else {
            switch (kbi) {
                case 0: kb = 0;        break;
                case 1: kb = ib - 1;   break;
                case 2: kb = ib;       break;
                case 3: kb = ib + 1;   break;
                case 4: kb = NB_ - 1;  break;
                default: kb = rb[kbi - 5];
            }
        }
        __syncthreads();   // protect ks/vs/sc reuse
        {   // load K (transposed) and V tiles
            const float* kbase = k + ((size_t)(b * S_ + kb * BLK_)) * D_ + h * DH_;
            const float* vbase = v + ((size_t)(b * S_ + kb * BLK_)) * D_ + h * DH_;
#pragma unroll
            for (int c = 0; c < 16; c += 4) {
                float4 f = *(const float4*)(kbase + r4 * D_ + g4 * 16 + c);
                ks[g4 * 16 + c + 0][r4] = f.x; ks[g4 * 16 + c + 1][r4] = f.y;
                ks[g4 * 16 + c + 2][r4] = f.z; ks[g4 * 16 + c + 3][r4] = f.w;
                float4 fv = *(const float4*)(vbase + r4 * D_ + g4 * 16 + c);
                *(float4*)&vs[r4][g4 * 16 + c] = fv;
            }
        }
        __syncthreads();

        // Phase A: S = Q K^T (thread: queries qi*4..+3 x keys ki*4..+3)
        float sac[4][4];
#pragma unroll
        for (int a = 0; a < 4; a++)
#pragma unroll
            for (int c = 0; c < 4; c++) sac[a][c] = 0.f;
#pragma unroll 8
        for (int d = 0; d < DH_; d++) {
            float4 qv = *(const float4*)&qs[d][qi * 4];
            float4 kv = *(const float4*)&ks[d][ki * 4];
            sac[0][0] = fmaf(qv.x, kv.x, sac[0][0]); sac[0][1] = fmaf(qv.x, kv.y, sac[0][1]);
            sac[0][2] = fmaf(qv.x, kv.z, sac[0][2]); sac[0][3] = fmaf(qv.x, kv.w, sac[0][3]);
            sac[1][0] = fmaf(qv.y, kv.x, sac[1][0]); sac[1][1] = fmaf(qv.y, kv.y, sac[1][1]);
            sac[1][2] = fmaf(qv.y, kv.z, sac[1][2]); sac[1][3] = fmaf(qv.y, kv.w, sac[1][3]);
            sac[2][0] = fmaf(qv.z, kv.x, sac[2][0]); sac[2][1] = fmaf(qv.z, kv.y, sac[2][1]);
            sac[2][2] = fmaf(qv.z, kv.z, sac[2][2]); sac[2][3] = fmaf(qv.z, kv.w, sac[2][3]);
            sac[3][0] = fmaf(qv.w, kv.x, sac[3][0]); sac[3][1] = fmaf(qv.w, kv.y, sac[3][1]);
            sac[3][2] = fmaf(qv.w, kv.z, sac[3][2]); sac[3][3] = fmaf(qv.w, kv.w, sac[3][3]);
        }
#pragma unroll
        for (int c = 0; c < 4; c++) {   // store scaled scores transposed sc[k][q]
            float4 o = {sac[0][c] * 0.125f, sac[1][c] * 0.125f,
                        sac[2][c] * 0.125f, sac[3][c] * 0.125f};
            *(float4*)&sc[ki * 4 + c][qi * 4] = o;
        }
        __syncthreads();

        // online softmax: thread (row r4, key group g4) handles 16 keys
        {
            float sv[16];
            float mloc = -1e30f;
#pragma unroll
            for (int j = 0; j < 16; j++) { sv[j] = sc[g4 * 16 + j][r4]; mloc = fmaxf(mloc, sv[j]); }
            mloc = fmaxf(mloc, __shfl_xor(mloc, 1, 4));
            mloc = fmaxf(mloc, __shfl_xor(mloc, 2, 4));
            float mold = m_s[r4];
            float mnew = fmaxf(mold, mloc);
            float ssum = 0.f;
#pragma unroll
            for (int j = 0; j < 16; j++) { float p = __expf(sv[j] - mnew); sv[j] = p; ssum += p; }
            ssum += __shfl_xor(ssum, 1, 4);
            ssum += __shfl_xor(ssum, 2, 4);
#pragma unroll
            for (int j = 0; j < 16; j++) sc[g4 * 16 + j][r4] = sv[j];
            if (g4 == 0) {
                float alpha = __expf(mold - mnew);
                al_s[r4] = alpha;
                m_s[r4]  = mnew;
                l_s[r4]  = l_s[r4] * alpha + ssum;
            }
        }
        __syncthreads();

        // Phase B: ctx = ctx*alpha + P V (thread: queries qi*4..+3 x dh ki*4..+3)
        {
            float al[4];
#pragma unroll
            for (int a = 0; a < 4; a++) al[a] = al_s[qi * 4 + a];
#pragma unroll
            for (int a = 0; a < 4; a++)
#pragma unroll
                for (int c = 0; c < 4; c++) ctxacc[a][c] *= al[a];
#pragma unroll 8
            for (int kc = 0; kc < BLK_; kc++) {
                float4 p4 = *(const float4*)&sc[kc][qi * 4];
                float4 v4 = *(const float4*)&vs[kc][ki * 4];
                ctxacc[0][0] = fmaf(p4.x, v4.x, ctxacc[0][0]); ctxacc[0][1] = fmaf(p4.x, v4.y, ctxacc[0][1]);
                ctxacc[0][2] = fmaf(p4.x, v4.z, ctxacc[0][2]); ctxacc[0][3] = fmaf(p4.x, v4.w, ctxacc[0][3]);
                ctxacc[1][0] = fmaf(p4.y, v4.x, ctxacc[1][0]); ctxacc[1][1] = fmaf(p4.y, v4.y, ctxacc[1][1]);
                ctxacc[1][2] = fmaf(p4.y, v4.z, ctxacc[1][2]); ctxacc[1][3] = fmaf(p4.y, v4.w, ctxacc[1][3]);
                ctxacc[2][0] = fmaf(p4.z, v4.x, ctxacc[2][0]); ctxacc[2][1] = fmaf(p4.z, v4.y, ctxacc[2][1]);
                ctxacc[2][2] = fmaf(p4.z, v4.z, ctxacc[2][2]); ctxacc[2][3] = fmaf(p4.z, v4.w, ctxacc[2][3]);
                ctxacc[3][0] = fmaf(p4.w, v4.x, ctxacc[3][0]); ctxacc[3][1] = fmaf(p4.w, v4.y, ctxacc[3][1]);
                ctxacc[3][2] = fmaf(p4.w, v4.z, ctxacc[3][2]); ctxacc[3][3] = fmaf(p4.w, v4.w, ctxacc[3][3]);
            }
        }
    }
    __syncthreads();
#pragma unroll
    for (int a = 0; a < 4; a++) {
        int qr = qi * 4 + a;
        float inv = 1.f / l_s[qr];
        float4 o = {ctxacc[a][0] * inv, ctxacc[a][1] * inv,
                    ctxacc[a][2] * inv, ctxacc[a][3] * inv};
        *(float4*)(ctx + ((size_t)(b * S_ + ib * BLK_ + qr)) * D_ + h * DH_ + ki * 4) = o;
    }
}

// ---------------------------------------------------------------- pooling + final dot

__global__ __launch_bounds__(256) void pool_kernel(
    const float* __restrict__ x, const float* __restrict__ fcw,
    float* __restrict__ acc)
{
    __shared__ float red[4];
    const int chunk = blockIdx.x, b = blockIdx.y;
    const int t = threadIdx.x;
    float s = 0.f;
    for (int sr = 0; sr < 128; sr++) {
        const float* xr = x + ((size_t)(b * S_ + chunk * 128 + sr)) * D_;
#pragma unroll
        for (int i = 0; i < 3; i++) {
            int d = t + i * 256;
            s += xr[d] * fcw[d];
        }
    }
    float tot = block_reduce_sum(s, red);
    if (t == 0) atomicAdd(&acc[b], tot);
}

__global__ void final_kernel(const float* __restrict__ acc,
                             const float* __restrict__ fcb,
                             float* __restrict__ out)
{
    if (threadIdx.x < B_) out[threadIdx.x] = acc[threadIdx.x] * (1.f / S_) + fcb[0];
}

// ---------------------------------------------------------------- launch

extern "C" void kernel_launch(void* const* d_in, const int* in_sizes, int n_in,
                              void* d_out, int out_size, void* d_ws, size_t ws_size,
                              hipStream_t stream)
{
    (void)in_sizes; (void)n_in; (void)out_size; (void)ws_size;
    const int*   ids  = (const int*)d_in[0];
    const int*   rnd  = (const int*)d_in[1];
    const float* etok = (const float*)d_in[2];
    const float* epos = (const float*)d_in[3];
    const float* lng  = (const float*)d_in[4];
    const float* lnb  = (const float*)d_in[5];
    const float* Wq   = (const float*)d_in[6];
    const float* bq   = (const float*)d_in[7];
    const float* Wk   = (const float*)d_in[8];
    const float* bk   = (const float*)d_in[9];
    const float* Wv   = (const float*)d_in[10];
    const float* bv   = (const float*)d_in[11];
    const float* Wo   = (const float*)d_in[12];
    const float* bo   = (const float*)d_in[13];
    const float* ln1g = (const float*)d_in[14];
    const float* ln1b = (const float*)d_in[15];
    const float* W1   = (const float*)d_in[16];
    const float* b1   = (const float*)d_in[17];
    const float* W2   = (const float*)d_in[18];
    const float* b2   = (const float*)d_in[19];
    const float* ln2g = (const float*)d_in[20];
    const float* ln2b = (const float*)d_in[21];
    const float* fcw  = (const float*)d_in[22];
    const float* fcb  = (const float*)d_in[23];
    float* out = (float*)d_out;

    // workspace layout (fp32): x | regionA (q,k,v + spare; aliased by ffh) | regionB (ctx/ff) | acc
    const size_t MD = (size_t)M_ * D_;
    float* x    = (float*)d_ws;
    float* regA = x + MD;
    float* qb   = regA;
    float* kb   = regA + MD;
    float* vb   = regA + 2 * MD;
    float* ffh  = regA;              // [M_, FF_] aliases q,k,v (+spare quarter)
    float* regB = regA + 4 * MD;     // ctx, then ff
    float* acc  = regB + MD;

    hipMemsetAsync(acc, 0, 2 * sizeof(float), stream);
    embed_ln_kernel<<<M_, 256, 0, stream>>>(ids, etok, epos, lng, lnb, x);

    dim3 gP(D_ / 128, M_ / 128);     // (6, 64)
    dim3 gF(FF_ / 128, M_ / 128);    // (24, 64)
    for (int l = 0; l < L_; l++) {
        const size_t wo  = (size_t)l * D_ * D_;
        const size_t vo  = (size_t)l * D_;
        gemm_kernel<0><<<gP, 256, 0, stream>>>(x, Wq + wo, bq + vo, qb, M_, D_, D_);
        gemm_kernel<0><<<gP, 256, 0, stream>>>(x, Wk + wo, bk + vo, kb, M_, D_, D_);
        gemm_kernel<0><<<gP, 256, 0, stream>>>(x, Wv + wo, bv + vo, vb, M_, D_, D_);
        attn_kernel<<<dim3(NB_, H_, B_), 256, 0, stream>>>(qb, kb, vb, rnd, regB);
        gemm_kernel<0><<<gP, 256, 0, stream>>>(regB, Wo + wo, bo + vo, qb, M_, D_, D_);
        add_ln_kernel<<<M_, 256, 0, stream>>>(x, qb, ln1g + vo, ln1b + vo);
        gemm_kernel<1><<<gF, 256, 0, stream>>>(x, W1 + (size_t)l * D_ * FF_, b1 + (size_t)l * FF_,
                                               ffh, M_, FF_, D_);
        gemm_kernel<0><<<gP, 256, 0, stream>>>(ffh, W2 + (size_t)l * FF_ * D_, b2 + vo,
                                               regB, M_, D_, FF_);
        add_ln_kernel<<<M_, 256, 0, stream>>>(x, regB, ln2g + vo, ln2b + vo);
    }
    pool_kernel<<<dim3(S_ / 128, B_), 256, 0, stream>>>(x, fcw, acc);
    final_kernel<<<1, 64, 0, stream>>>(acc, fcb, out);
}

// Round 2
// 4086.842 us; speedup vs baseline: 1.3798x; 1.3798x over previous
//
#include <hip/hip_runtime.h>
#include <hip/hip_bf16.h>
#include <math.h>

// Problem constants (BigBird regressor, B=2, S=4096)
#define D_    768
#define H_    12
#define DH_   64
#define BLK_  64
#define L_    2
#define R_    3
#define B_    2
#define S_    4096
#define NB_   64          // S_/BLK_
#define M_    (B_*S_)     // 8192 tokens
#define FF_   (4*D_)      // 3072
#define NCH_  8           // split-K chunks for full-attention rows

// ---------------------------------------------------------------- helpers

__device__ inline float gelu_f(float x) {
    float x3 = x * x * x;
    return 0.5f * x * (1.f + tanhf(0.7978845608f * (x + 0.044715f * x3)));
}

__device__ inline float block_reduce_sum(float v, float* red) {
#pragma unroll
    for (int o = 32; o > 0; o >>= 1) v += __shfl_xor(v, o, 64);
    int wv = threadIdx.x >> 6;
    if ((threadIdx.x & 63) == 0) red[wv] = v;
    __syncthreads();
    float tot = red[0] + red[1] + red[2] + red[3];
    __syncthreads();
    return tot;
}

// ---------------------------------------------------------------- embed+LN

__global__ __launch_bounds__(256) void embed_ln_kernel(
    const int* __restrict__ ids, const float* __restrict__ etok,
    const float* __restrict__ epos, const float* __restrict__ g,
    const float* __restrict__ bb, float* __restrict__ x)
{
    __shared__ float red[4];
    const int tok = blockIdx.x;
    const int s   = tok & (S_ - 1);
    const int id  = ids[tok];
    const int t   = threadIdx.x;
    float v[3];
    float sum = 0.f;
#pragma unroll
    for (int i = 0; i < 3; i++) {
        int d = t + i * 256;
        v[i] = etok[(size_t)id * D_ + d] + epos[(size_t)s * D_ + d];
        sum += v[i];
    }
    float mean = block_reduce_sum(sum, red) * (1.f / 768.f);
    float sq = 0.f;
#pragma unroll
    for (int i = 0; i < 3; i++) { float dd = v[i] - mean; sq += dd * dd; }
    float var = block_reduce_sum(sq, red) * (1.f / 768.f);
    float inv = rsqrtf(var + 1e-12f);
#pragma unroll
    for (int i = 0; i < 3; i++) {
        int d = t + i * 256;
        x[(size_t)tok * D_ + d] = (v[i] - mean) * inv * g[d] + bb[d];
    }
}

// ---------------------------------------------------------------- add + LN (in-place on x)

__global__ __launch_bounds__(256) void add_ln_kernel(
    float* __restrict__ x, const float* __restrict__ y,
    const float* __restrict__ g, const float* __restrict__ bb)
{
    __shared__ float red[4];
    const int tok = blockIdx.x;
    const int t   = threadIdx.x;
    float* xr = x + (size_t)tok * D_;
    const float* yr = y + (size_t)tok * D_;
    float v[3];
    float sum = 0.f;
#pragma unroll
    for (int i = 0; i < 3; i++) {
        int d = t + i * 256;
        v[i] = xr[d] + yr[d];
        sum += v[i];
    }
    float mean = block_reduce_sum(sum, red) * (1.f / 768.f);
    float sq = 0.f;
#pragma unroll
    for (int i = 0; i < 3; i++) { float dd = v[i] - mean; sq += dd * dd; }
    float var = block_reduce_sum(sq, red) * (1.f / 768.f);
    float inv = rsqrtf(var + 1e-12f);
#pragma unroll
    for (int i = 0; i < 3; i++) {
        int d = t + i * 256;
        xr[d] = (v[i] - mean) * inv * g[d] + bb[d];
    }
}

// ---------------------------------------------------------------- fp32 GEMM: C = A[M,K] @ W[K,N] + bias (+gelu)

template <int ACT>
__global__ __launch_bounds__(256) void gemm_kernel(
    const float* __restrict__ A, const float* __restrict__ W,
    const float* __restrict__ bias, float* __restrict__ C,
    int Md, int N, int K)
{
    __shared__ float As[16][132];   // [k][m] transposed
    __shared__ float Bs[16][132];   // [k][n]
    const int t  = threadIdx.x;
    const int tx = t & 15, ty = t >> 4;
    const int row0 = blockIdx.y * 128, col0 = blockIdx.x * 128;
    float acc[8][8];
#pragma unroll
    for (int i = 0; i < 8; i++)
#pragma unroll
        for (int j = 0; j < 8; j++) acc[i][j] = 0.f;

    for (int k0 = 0; k0 < K; k0 += 16) {
#pragma unroll
        for (int i = 0; i < 2; i++) {           // A tile: 128x16
            int e = t + i * 256;
            int r = e >> 2;
            int c = (e & 3) << 2;
            float4 a4 = *(const float4*)(A + (size_t)(row0 + r) * K + (k0 + c));
            As[c + 0][r] = a4.x; As[c + 1][r] = a4.y;
            As[c + 2][r] = a4.z; As[c + 3][r] = a4.w;
        }
#pragma unroll
        for (int i = 0; i < 2; i++) {           // B tile: 16x128
            int e = (t + i * 256) * 4;
            int r = e >> 7;
            int c = e & 127;
            float4 b4 = *(const float4*)(W + (size_t)(k0 + r) * N + (col0 + c));
            *(float4*)&Bs[r][c] = b4;
        }
        __syncthreads();
#pragma unroll
        for (int kk = 0; kk < 16; kk++) {
            float4 a0 = *(const float4*)&As[kk][ty * 8];
            float4 a1 = *(const float4*)&As[kk][ty * 8 + 4];
            float4 b0 = *(const float4*)&Bs[kk][tx * 8];
            float4 b1 = *(const float4*)&Bs[kk][tx * 8 + 4];
            float av[8] = {a0.x, a0.y, a0.z, a0.w, a1.x, a1.y, a1.z, a1.w};
            float bv[8] = {b0.x, b0.y, b0.z, b0.w, b1.x, b1.y, b1.z, b1.w};
#pragma unroll
            for (int i = 0; i < 8; i++)
#pragma unroll
                for (int j = 0; j < 8; j++)
                    acc[i][j] = fmaf(av[i], bv[j], acc[i][j]);
        }
        __syncthreads();
    }
#pragma unroll
    for (int i = 0; i < 8; i++) {
        size_t r = row0 + ty * 8 + i;
#pragma unroll
        for (int j = 0; j < 8; j += 4) {
            int c = col0 + tx * 8 + j;
            float4 o;
            o.x = acc[i][j + 0] + bias[c + 0];
            o.y = acc[i][j + 1] + bias[c + 1];
            o.z = acc[i][j + 2] + bias[c + 2];
            o.w = acc[i][j + 3] + bias[c + 3];
            if (ACT == 1) { o.x = gelu_f(o.x); o.y = gelu_f(o.y); o.z = gelu_f(o.z); o.w = gelu_f(o.w); }
            *(float4*)(C + r * N + c) = o;
        }
    }
}

// ---------------------------------------------------------------- attention core pieces
// thread map: qi = t>>4 (query group of 4 rows), ki = t&15 (key/dh group of 4)
// rows qi*4+a live in one 16-lane shfl group (width 16).

struct AttnState {
    float m[4], l[4], c[4][4];
};

// process one key block already staged in ks/vs; updates state, leaves P in sc
__device__ inline void attn_step(
    float (*qs)[BLK_ + 4], float (*ks)[BLK_ + 4],
    float (*vs)[DH_ + 4], float (*sc)[BLK_ + 4],
    AttnState& st, int qi, int ki)
{
    float sac[4][4];
#pragma unroll
    for (int a = 0; a < 4; a++)
#pragma unroll
        for (int c = 0; c < 4; c++) sac[a][c] = 0.f;
#pragma unroll 8
    for (int d = 0; d < DH_; d++) {
        float4 qv = *(const float4*)&qs[d][qi * 4];
        float4 kv = *(const float4*)&ks[d][ki * 4];
        sac[0][0] = fmaf(qv.x, kv.x, sac[0][0]); sac[0][1] = fmaf(qv.x, kv.y, sac[0][1]);
        sac[0][2] = fmaf(qv.x, kv.z, sac[0][2]); sac[0][3] = fmaf(qv.x, kv.w, sac[0][3]);
        sac[1][0] = fmaf(qv.y, kv.x, sac[1][0]); sac[1][1] = fmaf(qv.y, kv.y, sac[1][1]);
        sac[1][2] = fmaf(qv.y, kv.z, sac[1][2]); sac[1][3] = fmaf(qv.y, kv.w, sac[1][3]);
        sac[2][0] = fmaf(qv.z, kv.x, sac[2][0]); sac[2][1] = fmaf(qv.z, kv.y, sac[2][1]);
        sac[2][2] = fmaf(qv.z, kv.z, sac[2][2]); sac[2][3] = fmaf(qv.z, kv.w, sac[2][3]);
        sac[3][0] = fmaf(qv.w, kv.x, sac[3][0]); sac[3][1] = fmaf(qv.w, kv.y, sac[3][1]);
        sac[3][2] = fmaf(qv.w, kv.z, sac[3][2]); sac[3][3] = fmaf(qv.w, kv.w, sac[3][3]);
    }
    // in-register online softmax (rows replicated across 16 lanes sharing qi)
    float pr[4][4];
#pragma unroll
    for (int a = 0; a < 4; a++) {
        float s0 = sac[a][0] * 0.125f, s1 = sac[a][1] * 0.125f;
        float s2 = sac[a][2] * 0.125f, s3 = sac[a][3] * 0.125f;
        float lm = fmaxf(fmaxf(s0, s1), fmaxf(s2, s3));
        lm = fmaxf(lm, __shfl_xor(lm, 1, 16));
        lm = fmaxf(lm, __shfl_xor(lm, 2, 16));
        lm = fmaxf(lm, __shfl_xor(lm, 4, 16));
        lm = fmaxf(lm, __shfl_xor(lm, 8, 16));
        float mnew = fmaxf(st.m[a], lm);
        float al   = __expf(st.m[a] - mnew);
        pr[a][0] = __expf(s0 - mnew); pr[a][1] = __expf(s1 - mnew);
        pr[a][2] = __expf(s2 - mnew); pr[a][3] = __expf(s3 - mnew);
        float ss = pr[a][0] + pr[a][1] + pr[a][2] + pr[a][3];
        ss += __shfl_xor(ss, 1, 16);
        ss += __shfl_xor(ss, 2, 16);
        ss += __shfl_xor(ss, 4, 16);
        ss += __shfl_xor(ss, 8, 16);
        st.l[a] = st.l[a] * al + ss;
        st.m[a] = mnew;
#pragma unroll
        for (int j = 0; j < 4; j++) st.c[a][j] *= al;
    }
    // store P transposed: sc[k][q]
#pragma unroll
    for (int c = 0; c < 4; c++) {
        float4 o = {pr[0][c], pr[1][c], pr[2][c], pr[3][c]};
        *(float4*)&sc[ki * 4 + c][qi * 4] = o;
    }
    __syncthreads();
    // phase B: ctx += P V
#pragma unroll 8
    for (int kc = 0; kc < BLK_; kc++) {
        float4 p4 = *(const float4*)&sc[kc][qi * 4];
        float4 v4 = *(const float4*)&vs[kc][ki * 4];
        st.c[0][0] = fmaf(p4.x, v4.x, st.c[0][0]); st.c[0][1] = fmaf(p4.x, v4.y, st.c[0][1]);
        st.c[0][2] = fmaf(p4.x, v4.z, st.c[0][2]); st.c[0][3] = fmaf(p4.x, v4.w, st.c[0][3]);
        st.c[1][0] = fmaf(p4.y, v4.x, st.c[1][0]); st.c[1][1] = fmaf(p4.y, v4.y, st.c[1][1]);
        st.c[1][2] = fmaf(p4.y, v4.z, st.c[1][2]); st.c[1][3] = fmaf(p4.y, v4.w, st.c[1][3]);
        st.c[2][0] = fmaf(p4.z, v4.x, st.c[2][0]); st.c[2][1] = fmaf(p4.z, v4.y, st.c[2][1]);
        st.c[2][2] = fmaf(p4.z, v4.z, st.c[2][2]); st.c[2][3] = fmaf(p4.z, v4.w, st.c[2][3]);
        st.c[3][0] = fmaf(p4.w, v4.x, st.c[3][0]); st.c[3][1] = fmaf(p4.w, v4.y, st.c[3][1]);
        st.c[3][2] = fmaf(p4.w, v4.z, st.c[3][2]); st.c[3][3] = fmaf(p4.w, v4.w, st.c[3][3]);
    }
}

__device__ inline void load_q_tile(const float* __restrict__ q, int b, int qb, int h,
                                   float (*qs)[BLK_ + 4], int r4, int g4)
{
    const float* qbase = q + ((size_t)(b * S_ + qb * BLK_)) * D_ + h * DH_;
#pragma unroll
    for (int c = 0; c < 16; c += 4) {
        float4 f = *(const float4*)(qbase + r4 * D_ + g4 * 16 + c);
        qs[g4 * 16 + c + 0][r4] = f.x; qs[g4 * 16 + c + 1][r4] = f.y;
        qs[g4 * 16 + c + 2][r4] = f.z; qs[g4 * 16 + c + 3][r4] = f.w;
    }
}

__device__ inline void load_kv_tile(const float* __restrict__ k, const float* __restrict__ v,
                                    int b, int kb, int h,
                                    float (*ks)[BLK_ + 4], float (*vs)[DH_ + 4],
                                    int r4, int g4)
{
    const float* kbase = k + ((size_t)(b * S_ + kb * BLK_)) * D_ + h * DH_;
    const float* vbase = v + ((size_t)(b * S_ + kb * BLK_)) * D_ + h * DH_;
#pragma unroll
    for (int c = 0; c < 16; c += 4) {
        float4 f = *(const float4*)(kbase + r4 * D_ + g4 * 16 + c);
        ks[g4 * 16 + c + 0][r4] = f.x; ks[g4 * 16 + c + 1][r4] = f.y;
        ks[g4 * 16 + c + 2][r4] = f.z; ks[g4 * 16 + c + 3][r4] = f.w;
        float4 fv = *(const float4*)(vbase + r4 * D_ + g4 * 16 + c);
        *(float4*)&vs[r4][g4 * 16 + c] = fv;
    }
}

// ---------------------------------------------------------------- sparse attention (qblocks 1..62)

__global__ __launch_bounds__(256) void attn_sparse_kernel(
    const float* __restrict__ q, const float* __restrict__ k,
    const float* __restrict__ v, const int* __restrict__ rnd,
    float* __restrict__ ctx)
{
    __shared__ float qs[DH_][BLK_ + 4];
    __shared__ float ks[DH_][BLK_ + 4];
    __shared__ float vs[BLK_][DH_ + 4];
    __shared__ float sc[BLK_][BLK_ + 4];

    const int ib = blockIdx.x + 1, h = blockIdx.y, b = blockIdx.z;
    const int t  = threadIdx.x;
    const int r4 = t >> 2, g4 = t & 3;
    const int qi = t >> 4, ki = t & 15;

    load_q_tile(q, b, ib, h, qs, r4, g4);

    AttnState st;
#pragma unroll
    for (int a = 0; a < 4; a++) {
        st.m[a] = -1e30f; st.l[a] = 0.f;
#pragma unroll
        for (int j = 0; j < 4; j++) st.c[a][j] = 0.f;
    }

    const int* rp = rnd + ((size_t)(h * NB_ + ib)) * R_;
    int kbl[8] = {0, ib - 1, ib, ib + 1, NB_ - 1, rp[0], rp[1], rp[2]};

    for (int kbi = 0; kbi < 8; kbi++) {
        __syncthreads();
        load_kv_tile(k, v, b, kbl[kbi], h, ks, vs, r4, g4);
        __syncthreads();
        attn_step(qs, ks, vs, sc, st, qi, ki);
    }
#pragma unroll
    for (int a = 0; a < 4; a++) {
        int qr = qi * 4 + a;
        float inv = 1.f / st.l[a];
        float4 o = {st.c[a][0] * inv, st.c[a][1] * inv, st.c[a][2] * inv, st.c[a][3] * inv};
        *(float4*)(ctx + ((size_t)(b * S_ + ib * BLK_ + qr)) * D_ + h * DH_ + ki * 4) = o;
    }
}

// ---------------------------------------------------------------- full attention (qblocks 0,63) split-K partials

__global__ __launch_bounds__(256) void attn_full_kernel(
    const float* __restrict__ q, const float* __restrict__ k,
    const float* __restrict__ v,
    float* __restrict__ pctx, float* __restrict__ pm, float* __restrict__ pl)
{
    __shared__ float qs[DH_][BLK_ + 4];
    __shared__ float ks[DH_][BLK_ + 4];
    __shared__ float vs[BLK_][DH_ + 4];
    __shared__ float sc[BLK_][BLK_ + 4];

    const int chunk = blockIdx.x, h = blockIdx.y;
    const int b = blockIdx.z >> 1, qsel = blockIdx.z & 1;
    const int qb = qsel ? (NB_ - 1) : 0;
    const int t  = threadIdx.x;
    const int r4 = t >> 2, g4 = t & 3;
    const int qi = t >> 4, ki = t & 15;

    load_q_tile(q, b, qb, h, qs, r4, g4);

    AttnState st;
#pragma unroll
    for (int a = 0; a < 4; a++) {
        st.m[a] = -1e30f; st.l[a] = 0.f;
#pragma unroll
        for (int j = 0; j < 4; j++) st.c[a][j] = 0.f;
    }

    for (int kbi = 0; kbi < 8; kbi++) {
        __syncthreads();
        load_kv_tile(k, v, b, chunk * 8 + kbi, h, ks, vs, r4, g4);
        __syncthreads();
        attn_step(qs, ks, vs, sc, st, qi, ki);
    }
    const int ci = (((qsel * B_ + b) * H_ + h) * NCH_) + chunk;
#pragma unroll
    for (int a = 0; a < 4; a++) {
        int qr = qi * 4 + a;
        float4 o = {st.c[a][0], st.c[a][1], st.c[a][2], st.c[a][3]};
        *(float4*)(pctx + ((size_t)ci * BLK_ + qr) * DH_ + ki * 4) = o;
        if (ki == 0) {
            pm[(size_t)ci * BLK_ + qr] = st.m[a];
            pl[(size_t)ci * BLK_ + qr] = st.l[a];
        }
    }
}

__global__ __launch_bounds__(256) void attn_combine_kernel(
    const float* __restrict__ pctx, const float* __restrict__ pm,
    const float* __restrict__ pl, float* __restrict__ ctx)
{
    const int qsel = blockIdx.x, h = blockIdx.y, b = blockIdx.z;
    const int qb = qsel ? (NB_ - 1) : 0;
    const int t = threadIdx.x;
    const int row = t >> 2, q4 = t & 3;
    const int cbase = ((qsel * B_ + b) * H_ + h) * NCH_;

    float mv[NCH_], lv[NCH_];
    float M = -1e30f;
#pragma unroll
    for (int c = 0; c < NCH_; c++) {
        mv[c] = pm[(size_t)(cbase + c) * BLK_ + row];
        lv[c] = pl[(size_t)(cbase + c) * BLK_ + row];
        M = fmaxf(M, mv[c]);
    }
    float L = 0.f;
    float w[NCH_];
#pragma unroll
    for (int c = 0; c < NCH_; c++) { w[c] = __expf(mv[c] - M); L += lv[c] * w[c]; }
    float acc[16];
#pragma unroll
    for (int j = 0; j < 16; j++) acc[j] = 0.f;
#pragma unroll
    for (int c = 0; c < NCH_; c++) {
        const float* src = pctx + ((size_t)(cbase + c) * BLK_ + row) * DH_ + q4 * 16;
#pragma unroll
        for (int jj = 0; jj < 4; jj++) {
            float4 f = *(const float4*)(src + jj * 4);
            acc[jj * 4 + 0] = fmaf(f.x, w[c], acc[jj * 4 + 0]);
            acc[jj * 4 + 1] = fmaf(f.y, w[c], acc[jj * 4 + 1]);
            acc[jj * 4 + 2] = fmaf(f.z, w[c], acc[jj * 4 + 2]);
            acc[jj * 4 + 3] = fmaf(f.w, w[c], acc[jj * 4 + 3]);
        }
    }
    float invL = 1.f / L;
    float* dst = ctx + ((size_t)(b * S_ + qb * BLK_ + row)) * D_ + h * DH_ + q4 * 16;
#pragma unroll
    for (int jj = 0; jj < 4; jj++) {
        float4 o = {acc[jj * 4 + 0] * invL, acc[jj * 4 + 1] * invL,
                    acc[jj * 4 + 2] * invL, acc[jj * 4 + 3] * invL};
        *(float4*)(dst + jj * 4) = o;
    }
}

// ---------------------------------------------------------------- pooling + final dot

__global__ __launch_bounds__(256) void pool_kernel(
    const float* __restrict__ x, const float* __restrict__ fcw,
    float* __restrict__ acc)
{
    __shared__ float red[4];
    const int chunk = blockIdx.x, b = blockIdx.y;
    const int t = threadIdx.x;
    float s = 0.f;
    for (int sr = 0; sr < 128; sr++) {
        const float* xr = x + ((size_t)(b * S_ + chunk * 128 + sr)) * D_;
#pragma unroll
        for (int i = 0; i < 3; i++) {
            int d = t + i * 256;
            s += xr[d] * fcw[d];
        }
    }
    float tot = block_reduce_sum(s, red);
    if (t == 0) atomicAdd(&acc[b], tot);
}

__global__ void final_kernel(const float* __restrict__ acc,
                             const float* __restrict__ fcb,
                             float* __restrict__ out)
{
    if (threadIdx.x < B_) out[threadIdx.x] = acc[threadIdx.x] * (1.f / S_) + fcb[0];
}

// ---------------------------------------------------------------- launch

extern "C" void kernel_launch(void* const* d_in, const int* in_sizes, int n_in,
                              void* d_out, int out_size, void* d_ws, size_t ws_size,
                              hipStream_t stream)
{
    (void)in_sizes; (void)n_in; (void)out_size; (void)ws_size;
    const int*   ids  = (const int*)d_in[0];
    const int*   rnd  = (const int*)d_in[1];
    const float* etok = (const float*)d_in[2];
    const float* epos = (const float*)d_in[3];
    const float* lng  = (const float*)d_in[4];
    const float* lnb  = (const float*)d_in[5];
    const float* Wq   = (const float*)d_in[6];
    const float* bq   = (const float*)d_in[7];
    const float* Wk   = (const float*)d_in[8];
    const float* bk   = (const float*)d_in[9];
    const float* Wv   = (const float*)d_in[10];
    const float* bv   = (const float*)d_in[11];
    const float* Wo   = (const float*)d_in[12];
    const float* bo   = (const float*)d_in[13];
    const float* ln1g = (const float*)d_in[14];
    const float* ln1b = (const float*)d_in[15];
    const float* W1   = (const float*)d_in[16];
    const float* b1   = (const float*)d_in[17];
    const float* W2   = (const float*)d_in[18];
    const float* b2   = (const float*)d_in[19];
    const float* ln2g = (const float*)d_in[20];
    const float* ln2b = (const float*)d_in[21];
    const float* fcw  = (const float*)d_in[22];
    const float* fcb  = (const float*)d_in[23];
    float* out = (float*)d_out;

    // workspace layout (fp32): x | regA (q,k,v | partials-in-Q4; aliased by ffh) | regB (ctx/ff) | acc
    const size_t MD = (size_t)M_ * D_;
    float* x    = (float*)d_ws;
    float* regA = x + MD;
    float* qb   = regA;
    float* kb   = regA + MD;
    float* vb   = regA + 2 * MD;
    float* pctx = regA + 3 * MD;                       // 2*2*12*8*4096 = 1.57M floats < MD
    float* pm   = pctx + (size_t)2 * B_ * H_ * NCH_ * BLK_ * DH_;
    float* pl   = pm + (size_t)2 * B_ * H_ * NCH_ * BLK_;
    float* ffh  = regA;              // [M_, FF_] aliases q,k,v,partials
    float* regB = regA + 4 * MD;     // ctx, then ff
    float* acc  = regB + MD;

    hipMemsetAsync(acc, 0, 2 * sizeof(float), stream);
    embed_ln_kernel<<<M_, 256, 0, stream>>>(ids, etok, epos, lng, lnb, x);

    dim3 gP(D_ / 128, M_ / 128);     // (6, 64)
    dim3 gF(FF_ / 128, M_ / 128);    // (24, 64)
    for (int l = 0; l < L_; l++) {
        const size_t wo  = (size_t)l * D_ * D_;
        const size_t vo  = (size_t)l * D_;
        gemm_kernel<0><<<gP, 256, 0, stream>>>(x, Wq + wo, bq + vo, qb, M_, D_, D_);
        gemm_kernel<0><<<gP, 256, 0, stream>>>(x, Wk + wo, bk + vo, kb, M_, D_, D_);
        gemm_kernel<0><<<gP, 256, 0, stream>>>(x, Wv + wo, bv + vo, vb, M_, D_, D_);
        attn_sparse_kernel<<<dim3(NB_ - 2, H_, B_), 256, 0, stream>>>(qb, kb, vb, rnd, regB);
        attn_full_kernel<<<dim3(NCH_, H_, B_ * 2), 256, 0, stream>>>(qb, kb, vb, pctx, pm, pl);
        attn_combine_kernel<<<dim3(2, H_, B_), 256, 0, stream>>>(pctx, pm, pl, regB);
        gemm_kernel<0><<<gP, 256, 0, stream>>>(regB, Wo + wo, bo + vo, qb, M_, D_, D_);
        add_ln_kernel<<<M_, 256, 0, stream>>>(x, qb, ln1g + vo, ln1b + vo);
        gemm_kernel<1><<<gF, 256, 0, stream>>>(x, W1 + (size_t)l * D_ * FF_, b1 + (size_t)l * FF_,
                                               ffh, M_, FF_, D_);
        gemm_kernel<0><<<gP, 256, 0, stream>>>(ffh, W2 + (size_t)l * FF_ * D_, b2 + vo,
                                               regB, M_, D_, FF_);
        add_ln_kernel<<<M_, 256, 0, stream>>>(x, regB, ln2g + vo, ln2b + vo);
    }
    pool_kernel<<<dim3(S_ / 128, B_), 256, 0, stream>>>(x, fcw, acc);
    final_kernel<<<1, 64, 0, stream>>>(acc, fcb, out);
}

// Round 3
// 1358.713 us; speedup vs baseline: 4.1504x; 3.0079x over previous
//
#include <hip/hip_runtime.h>
#include <hip/hip_bf16.h>
#include <math.h>

// Problem constants (BigBird regressor, B=2, S=4096)
#define D_    768
#define H_    12
#define DH_   64
#define BLK_  64
#define L_    2
#define R_    3
#define B_    2
#define S_    4096
#define NB_   64          // S_/BLK_
#define M_    (B_*S_)     // 8192 tokens
#define FF_   (4*D_)      // 3072
#define NCH_  8           // split-K chunks for full-attention rows

typedef unsigned short u16;
typedef __bf16 bf16x8 __attribute__((ext_vector_type(8)));
typedef float  f32x4  __attribute__((ext_vector_type(4)));

// ---------------------------------------------------------------- helpers

__device__ inline float gelu_f(float x) {
    float x3 = x * x * x;
    return 0.5f * x * (1.f + tanhf(0.7978845608f * (x + 0.044715f * x3)));
}

__device__ inline float bf2f(u16 u) {
    unsigned v = ((unsigned)u) << 16;
    return __uint_as_float(v);
}

__device__ inline u16 f2bf(float f) {
    union { __hip_bfloat16 h; u16 u; } cv;
    cv.h = __float2bfloat16(f);
    return cv.u;
}

__device__ inline float block_reduce_sum(float v, float* red) {
#pragma unroll
    for (int o = 32; o > 0; o >>= 1) v += __shfl_xor(v, o, 64);
    int wv = threadIdx.x >> 6;
    if ((threadIdx.x & 63) == 0) red[wv] = v;
    __syncthreads();
    float tot = red[0] + red[1] + red[2] + red[3];
    __syncthreads();
    return tot;
}

// ---------------------------------------------------------------- weight transpose-cast: in fp32 [K,N] -> out bf16 [N,K]

__global__ __launch_bounds__(256) void tcast_kernel(
    const float* __restrict__ in, u16* __restrict__ out, int K, int N)
{
    __shared__ float tile[32][33];
    const int n0 = blockIdx.x * 32, k0 = blockIdx.y * 32;
    const int tx = threadIdx.x & 31, ty = threadIdx.x >> 5;
#pragma unroll
    for (int p = 0; p < 4; p++)
        tile[ty + p * 8][tx] = in[(size_t)(k0 + ty + p * 8) * N + n0 + tx];
    __syncthreads();
#pragma unroll
    for (int p = 0; p < 4; p++)
        out[(size_t)(n0 + ty + p * 8) * K + k0 + tx] = f2bf(tile[tx][ty + p * 8]);
}

// ---------------------------------------------------------------- embed+LN (writes fp32 x and bf16 xb)

__global__ __launch_bounds__(256) void embed_ln_kernel(
    const int* __restrict__ ids, const float* __restrict__ etok,
    const float* __restrict__ epos, const float* __restrict__ g,
    const float* __restrict__ bb, float* __restrict__ x, u16* __restrict__ xb)
{
    __shared__ float red[4];
    const int tok = blockIdx.x;
    const int s   = tok & (S_ - 1);
    const int id  = ids[tok];
    const int t   = threadIdx.x;
    float v[3];
    float sum = 0.f;
#pragma unroll
    for (int i = 0; i < 3; i++) {
        int d = t + i * 256;
        v[i] = etok[(size_t)id * D_ + d] + epos[(size_t)s * D_ + d];
        sum += v[i];
    }
    float mean = block_reduce_sum(sum, red) * (1.f / 768.f);
    float sq = 0.f;
#pragma unroll
    for (int i = 0; i < 3; i++) { float dd = v[i] - mean; sq += dd * dd; }
    float var = block_reduce_sum(sq, red) * (1.f / 768.f);
    float inv = rsqrtf(var + 1e-12f);
#pragma unroll
    for (int i = 0; i < 3; i++) {
        int d = t + i * 256;
        float o = (v[i] - mean) * inv * g[d] + bb[d];
        x[(size_t)tok * D_ + d] = o;
        xb[(size_t)tok * D_ + d] = f2bf(o);
    }
}

// ---------------------------------------------------------------- add + LN (in-place on x; also writes bf16 xb)

__global__ __launch_bounds__(256) void add_ln_kernel(
    float* __restrict__ x, const float* __restrict__ y,
    const float* __restrict__ g, const float* __restrict__ bb,
    u16* __restrict__ xb)
{
    __shared__ float red[4];
    const int tok = blockIdx.x;
    const int t   = threadIdx.x;
    float* xr = x + (size_t)tok * D_;
    const float* yr = y + (size_t)tok * D_;
    float v[3];
    float sum = 0.f;
#pragma unroll
    for (int i = 0; i < 3; i++) {
        int d = t + i * 256;
        v[i] = xr[d] + yr[d];
        sum += v[i];
    }
    float mean = block_reduce_sum(sum, red) * (1.f / 768.f);
    float sq = 0.f;
#pragma unroll
    for (int i = 0; i < 3; i++) { float dd = v[i] - mean; sq += dd * dd; }
    float var = block_reduce_sum(sq, red) * (1.f / 768.f);
    float inv = rsqrtf(var + 1e-12f);
#pragma unroll
    for (int i = 0; i < 3; i++) {
        int d = t + i * 256;
        float o = (v[i] - mean) * inv * g[d] + bb[d];
        xr[d] = o;
        xb[(size_t)tok * D_ + d] = f2bf(o);
    }
}

// ---------------------------------------------------------------- bf16 MFMA GEMM: C = A[M,K](bf16) @ Wt[N,K](bf16)^T + bias
// 128x128 tile, BK=32, 256 threads = 4 waves (2x2), each wave 64x64 via 4x4 of 16x16x32 MFMA.
// LDS in fragment-major chunk order: chunk(r16,q,i) at [(r16*4+q)*16+i]*16B -> conflict-free b128 reads.

template <int ACT, int OBF>
__global__ __launch_bounds__(256) void gemm_bf16_kernel(
    const u16* __restrict__ A, const u16* __restrict__ Wt,
    const float* __restrict__ bias, void* __restrict__ Cv,
    int N, int K)
{
    __shared__ __align__(16) u16 As[4096];   // 128x32 bf16, fragment-major
    __shared__ __align__(16) u16 Bs[4096];
    const int t = threadIdx.x;
    const int row0 = blockIdx.y * 128, col0 = blockIdx.x * 128;
    const int w = t >> 6, lane = t & 63;
    const int wr = w >> 1, wc = w & 1;
    const int i16 = lane & 15, qd = lane >> 4;

    const f32x4 zero = {0.f, 0.f, 0.f, 0.f};
    f32x4 acc[4][4];
#pragma unroll
    for (int r = 0; r < 4; r++)
#pragma unroll
        for (int c = 0; c < 4; c++) acc[r][c] = zero;

    // staging map: chunk e in [0,512): row = e>>2, kc = e&3 ; LDS chunk = (row>>4)*64 + kc*16 + (row&15)
    const int e0 = t, e1 = t + 256;
    const int ra0 = e0 >> 2, ca0 = e0 & 3;
    const int ra1 = e1 >> 2, ca1 = e1 & 3;
    const int lds0 = ((ra0 >> 4) * 64 + ca0 * 16 + (ra0 & 15)) * 8;
    const int lds1 = ((ra1 >> 4) * 64 + ca1 * 16 + (ra1 & 15)) * 8;

    uint4 a0, a1, b0, b1;
    {
        a0 = *(const uint4*)(A + (size_t)(row0 + ra0) * K + ca0 * 8);
        a1 = *(const uint4*)(A + (size_t)(row0 + ra1) * K + ca1 * 8);
        b0 = *(const uint4*)(Wt + (size_t)(col0 + ra0) * K + ca0 * 8);
        b1 = *(const uint4*)(Wt + (size_t)(col0 + ra1) * K + ca1 * 8);
    }

    for (int k0 = 0; k0 < K; k0 += 32) {
        __syncthreads();   // previous iteration's frag reads complete
        *(uint4*)&As[lds0] = a0;
        *(uint4*)&As[lds1] = a1;
        *(uint4*)&Bs[lds0] = b0;
        *(uint4*)&Bs[lds1] = b1;
        __syncthreads();
        if (k0 + 32 < K) {  // prefetch next tile while computing
            int kn = k0 + 32;
            a0 = *(const uint4*)(A + (size_t)(row0 + ra0) * K + kn + ca0 * 8);
            a1 = *(const uint4*)(A + (size_t)(row0 + ra1) * K + kn + ca1 * 8);
            b0 = *(const uint4*)(Wt + (size_t)(col0 + ra0) * K + kn + ca0 * 8);
            b1 = *(const uint4*)(Wt + (size_t)(col0 + ra1) * K + kn + ca1 * 8);
        }
        bf16x8 af[4], bfr[4];
#pragma unroll
        for (int r = 0; r < 4; r++)
            af[r] = *(const bf16x8*)&As[(((wr * 4 + r) * 4 + qd) * 16 + i16) * 8];
#pragma unroll
        for (int c = 0; c < 4; c++)
            bfr[c] = *(const bf16x8*)&Bs[(((wc * 4 + c) * 4 + qd) * 16 + i16) * 8];
#pragma unroll
        for (int r = 0; r < 4; r++)
#pragma unroll
            for (int c = 0; c < 4; c++)
                acc[r][c] = __builtin_amdgcn_mfma_f32_16x16x32_bf16(af[r], bfr[c], acc[r][c], 0, 0, 0);
    }

    // epilogue: C/D layout col=lane&15, row=qd*4+reg
#pragma unroll
    for (int c = 0; c < 4; c++) {
        int colg = col0 + wc * 64 + c * 16 + i16;
        float bsv = bias[colg];
#pragma unroll
        for (int r = 0; r < 4; r++) {
            int rowb = row0 + wr * 64 + r * 16 + qd * 4;
#pragma unroll
            for (int p = 0; p < 4; p++) {
                float val = acc[r][c][p] + bsv;
                if (ACT == 1) val = gelu_f(val);
                if (OBF == 1)
                    ((u16*)Cv)[(size_t)(rowb + p) * N + colg] = f2bf(val);
                else
                    ((float*)Cv)[(size_t)(rowb + p) * N + colg] = val;
            }
        }
    }
}

// ---------------------------------------------------------------- attention core (fp32 math, bf16 q/k/v/ctx)
// thread map: qi = t>>4 (query group of 4 rows), ki = t&15 (key/dh group of 4)

struct AttnState {
    float m[4], l[4], c[4][4];
};

__device__ inline void attn_step(
    float (*qs)[BLK_ + 4], float (*ks)[BLK_ + 4],
    float (*vs)[DH_ + 4], float (*sc)[BLK_ + 4],
    AttnState& st, int qi, int ki)
{
    float sac[4][4];
#pragma unroll
    for (int a = 0; a < 4; a++)
#pragma unroll
        for (int c = 0; c < 4; c++) sac[a][c] = 0.f;
#pragma unroll 8
    for (int d = 0; d < DH_; d++) {
        float4 qv = *(const float4*)&qs[d][qi * 4];
        float4 kv = *(const float4*)&ks[d][ki * 4];
        sac[0][0] = fmaf(qv.x, kv.x, sac[0][0]); sac[0][1] = fmaf(qv.x, kv.y, sac[0][1]);
        sac[0][2] = fmaf(qv.x, kv.z, sac[0][2]); sac[0][3] = fmaf(qv.x, kv.w, sac[0][3]);
        sac[1][0] = fmaf(qv.y, kv.x, sac[1][0]); sac[1][1] = fmaf(qv.y, kv.y, sac[1][1]);
        sac[1][2] = fmaf(qv.y, kv.z, sac[1][2]); sac[1][3] = fmaf(qv.y, kv.w, sac[1][3]);
        sac[2][0] = fmaf(qv.z, kv.x, sac[2][0]); sac[2][1] = fmaf(qv.z, kv.y, sac[2][1]);
        sac[2][2] = fmaf(qv.z, kv.z, sac[2][2]); sac[2][3] = fmaf(qv.z, kv.w, sac[2][3]);
        sac[3][0] = fmaf(qv.w, kv.x, sac[3][0]); sac[3][1] = fmaf(qv.w, kv.y, sac[3][1]);
        sac[3][2] = fmaf(qv.w, kv.z, sac[3][2]); sac[3][3] = fmaf(qv.w, kv.w, sac[3][3]);
    }
    float pr[4][4];
#pragma unroll
    for (int a = 0; a < 4; a++) {
        float s0 = sac[a][0] * 0.125f, s1 = sac[a][1] * 0.125f;
        float s2 = sac[a][2] * 0.125f, s3 = sac[a][3] * 0.125f;
        float lm = fmaxf(fmaxf(s0, s1), fmaxf(s2, s3));
        lm = fmaxf(lm, __shfl_xor(lm, 1, 16));
        lm = fmaxf(lm, __shfl_xor(lm, 2, 16));
        lm = fmaxf(lm, __shfl_xor(lm, 4, 16));
        lm = fmaxf(lm, __shfl_xor(lm, 8, 16));
        float mnew = fmaxf(st.m[a], lm);
        float al   = __expf(st.m[a] - mnew);
        pr[a][0] = __expf(s0 - mnew); pr[a][1] = __expf(s1 - mnew);
        pr[a][2] = __expf(s2 - mnew); pr[a][3] = __expf(s3 - mnew);
        float ss = pr[a][0] + pr[a][1] + pr[a][2] + pr[a][3];
        ss += __shfl_xor(ss, 1, 16);
        ss += __shfl_xor(ss, 2, 16);
        ss += __shfl_xor(ss, 4, 16);
        ss += __shfl_xor(ss, 8, 16);
        st.l[a] = st.l[a] * al + ss;
        st.m[a] = mnew;
#pragma unroll
        for (int j = 0; j < 4; j++) st.c[a][j] *= al;
    }
#pragma unroll
    for (int c = 0; c < 4; c++) {
        float4 o = {pr[0][c], pr[1][c], pr[2][c], pr[3][c]};
        *(float4*)&sc[ki * 4 + c][qi * 4] = o;
    }
    __syncthreads();
#pragma unroll 8
    for (int kc = 0; kc < BLK_; kc++) {
        float4 p4 = *(const float4*)&sc[kc][qi * 4];
        float4 v4 = *(const float4*)&vs[kc][ki * 4];
        st.c[0][0] = fmaf(p4.x, v4.x, st.c[0][0]); st.c[0][1] = fmaf(p4.x, v4.y, st.c[0][1]);
        st.c[0][2] = fmaf(p4.x, v4.z, st.c[0][2]); st.c[0][3] = fmaf(p4.x, v4.w, st.c[0][3]);
        st.c[1][0] = fmaf(p4.y, v4.x, st.c[1][0]); st.c[1][1] = fmaf(p4.y, v4.y, st.c[1][1]);
        st.c[1][2] = fmaf(p4.y, v4.z, st.c[1][2]); st.c[1][3] = fmaf(p4.y, v4.w, st.c[1][3]);
        st.c[2][0] = fmaf(p4.z, v4.x, st.c[2][0]); st.c[2][1] = fmaf(p4.z, v4.y, st.c[2][1]);
        st.c[2][2] = fmaf(p4.z, v4.z, st.c[2][2]); st.c[2][3] = fmaf(p4.z, v4.w, st.c[2][3]);
        st.c[3][0] = fmaf(p4.w, v4.x, st.c[3][0]); st.c[3][1] = fmaf(p4.w, v4.y, st.c[3][1]);
        st.c[3][2] = fmaf(p4.w, v4.z, st.c[3][2]); st.c[3][3] = fmaf(p4.w, v4.w, st.c[3][3]);
    }
}

__device__ inline void load_q_bf(const u16* __restrict__ q, int b, int qblk, int h,
                                 float (*qs)[BLK_ + 4], int t)
{
    const u16* base = q + ((size_t)(b * S_ + qblk * BLK_)) * D_ + h * DH_;
    for (int e = t; e < 512; e += 256) {
        int row = e >> 3, ch = e & 7;
        uint4 u = *(const uint4*)(base + (size_t)row * D_ + ch * 8);
        const u16* us = (const u16*)&u;
#pragma unroll
        for (int j = 0; j < 8; j++) qs[ch * 8 + j][row] = bf2f(us[j]);
    }
}

__device__ inline void load_kv_bf(const u16* __restrict__ k, const u16* __restrict__ v,
                                  int b, int kblk, int h,
                                  float (*ks)[BLK_ + 4], float (*vs)[DH_ + 4], int t)
{
    const u16* kbase = k + ((size_t)(b * S_ + kblk * BLK_)) * D_ + h * DH_;
    const u16* vbase = v + ((size_t)(b * S_ + kblk * BLK_)) * D_ + h * DH_;
    for (int e = t; e < 512; e += 256) {
        int row = e >> 3, ch = e & 7;
        uint4 u = *(const uint4*)(kbase + (size_t)row * D_ + ch * 8);
        const u16* us = (const u16*)&u;
#pragma unroll
        for (int j = 0; j < 8; j++) ks[ch * 8 + j][row] = bf2f(us[j]);
        uint4 w = *(const uint4*)(vbase + (size_t)row * D_ + ch * 8);
        const u16* ws2 = (const u16*)&w;
#pragma unroll
        for (int j = 0; j < 8; j++) vs[row][ch * 8 + j] = bf2f(ws2[j]);
    }
}

// ---------------------------------------------------------------- sparse attention (qblocks 1..62), bf16 out

__global__ __launch_bounds__(256) void attn_sparse_kernel(
    const u16* __restrict__ q, const u16* __restrict__ k,
    const u16* __restrict__ v, const int* __restrict__ rnd,
    u16* __restrict__ ctx)
{
    __shared__ float qs[DH_][BLK_ + 4];
    __shared__ float ks[DH_][BLK_ + 4];
    __shared__ float vs[BLK_][DH_ + 4];
    __shared__ float sc[BLK_][BLK_ + 4];

    const int ib = blockIdx.x + 1, h = blockIdx.y, b = blockIdx.z;
    const int t  = threadIdx.x;
    const int qi = t >> 4, ki = t & 15;

    load_q_bf(q, b, ib, h, qs, t);

    AttnState st;
#pragma unroll
    for (int a = 0; a < 4; a++) {
        st.m[a] = -1e30f; st.l[a] = 0.f;
#pragma unroll
        for (int j = 0; j < 4; j++) st.c[a][j] = 0.f;
    }

    const int* rp = rnd + ((size_t)(h * NB_ + ib)) * R_;
    int kbl[8] = {0, ib - 1, ib, ib + 1, NB_ - 1, rp[0], rp[1], rp[2]};

    for (int kbi = 0; kbi < 8; kbi++) {
        __syncthreads();
        load_kv_bf(k, v, b, kbl[kbi], h, ks, vs, t);
        __syncthreads();
        attn_step(qs, ks, vs, sc, st, qi, ki);
    }
#pragma unroll
    for (int a = 0; a < 4; a++) {
        int qr = qi * 4 + a;
        float inv = 1.f / st.l[a];
        uint2 o;
        o.x = (unsigned)f2bf(st.c[a][0] * inv) | ((unsigned)f2bf(st.c[a][1] * inv) << 16);
        o.y = (unsigned)f2bf(st.c[a][2] * inv) | ((unsigned)f2bf(st.c[a][3] * inv) << 16);
        *(uint2*)(ctx + ((size_t)(b * S_ + ib * BLK_ + qr)) * D_ + h * DH_ + ki * 4) = o;
    }
}

// ---------------------------------------------------------------- full attention (qblocks 0,63) split-K partials

__global__ __launch_bounds__(256) void attn_full_kernel(
    const u16* __restrict__ q, const u16* __restrict__ k,
    const u16* __restrict__ v,
    float* __restrict__ pctx, float* __restrict__ pm, float* __restrict__ pl)
{
    __shared__ float qs[DH_][BLK_ + 4];
    __shared__ float ks[DH_][BLK_ + 4];
    __shared__ float vs[BLK_][DH_ + 4];
    __shared__ float sc[BLK_][BLK_ + 4];

    const int chunk = blockIdx.x, h = blockIdx.y;
    const int b = blockIdx.z >> 1, qsel = blockIdx.z & 1;
    const int qb = qsel ? (NB_ - 1) : 0;
    const int t  = threadIdx.x;
    const int qi = t >> 4, ki = t & 15;

    load_q_bf(q, b, qb, h, qs, t);

    AttnState st;
#pragma unroll
    for (int a = 0; a < 4; a++) {
        st.m[a] = -1e30f; st.l[a] = 0.f;
#pragma unroll
        for (int j = 0; j < 4; j++) st.c[a][j] = 0.f;
    }

    for (int kbi = 0; kbi < 8; kbi++) {
        __syncthreads();
        load_kv_bf(k, v, b, chunk * 8 + kbi, h, ks, vs, t);
        __syncthreads();
        attn_step(qs, ks, vs, sc, st, qi, ki);
    }
    const int ci = (((qsel * B_ + b) * H_ + h) * NCH_) + chunk;
#pragma unroll
    for (int a = 0; a < 4; a++) {
        int qr = qi * 4 + a;
        float4 o = {st.c[a][0], st.c[a][1], st.c[a][2], st.c[a][3]};
        *(float4*)(pctx + ((size_t)ci * BLK_ + qr) * DH_ + ki * 4) = o;
        if (ki == 0) {
            pm[(size_t)ci * BLK_ + qr] = st.m[a];
            pl[(size_t)ci * BLK_ + qr] = st.l[a];
        }
    }
}

__global__ __launch_bounds__(256) void attn_combine_kernel(
    const float* __restrict__ pctx, const float* __restrict__ pm,
    const float* __restrict__ pl, u16* __restrict__ ctx)
{
    const int qsel = blockIdx.x, h = blockIdx.y, b = blockIdx.z;
    const int qb = qsel ? (NB_ - 1) : 0;
    const int t = threadIdx.x;
    const int row = t >> 2, q4 = t & 3;
    const int cbase = ((qsel * B_ + b) * H_ + h) * NCH_;

    float mv[NCH_], lv[NCH_];
    float M = -1e30f;
#pragma unroll
    for (int c = 0; c < NCH_; c++) {
        mv[c] = pm[(size_t)(cbase + c) * BLK_ + row];
        lv[c] = pl[(size_t)(cbase + c) * BLK_ + row];
        M = fmaxf(M, mv[c]);
    }
    float L = 0.f;
    float w[NCH_];
#pragma unroll
    for (int c = 0; c < NCH_; c++) { w[c] = __expf(mv[c] - M); L += lv[c] * w[c]; }
    float acc[16];
#pragma unroll
    for (int j = 0; j < 16; j++) acc[j] = 0.f;
#pragma unroll
    for (int c = 0; c < NCH_; c++) {
        const float* src = pctx + ((size_t)(cbase + c) * BLK_ + row) * DH_ + q4 * 16;
#pragma unroll
        for (int jj = 0; jj < 4; jj++) {
            float4 f = *(const float4*)(src + jj * 4);
            acc[jj * 4 + 0] = fmaf(f.x, w[c], acc[jj * 4 + 0]);
            acc[jj * 4 + 1] = fmaf(f.y, w[c], acc[jj * 4 + 1]);
            acc[jj * 4 + 2] = fmaf(f.z, w[c], acc[jj * 4 + 2]);
            acc[jj * 4 + 3] = fmaf(f.w, w[c], acc[jj * 4 + 3]);
        }
    }
    float invL = 1.f / L;
    u16* dst = ctx + ((size_t)(b * S_ + qb * BLK_ + row)) * D_ + h * DH_ + q4 * 16;
    uint4 o0, o1;
    unsigned* op = &o0.x;
#pragma unroll
    for (int g = 0; g < 8; g++) {
        unsigned lo = (unsigned)f2bf(acc[g * 2 + 0] * invL);
        unsigned hi = (unsigned)f2bf(acc[g * 2 + 1] * invL);
        unsigned pk = lo | (hi << 16);
        if (g < 4) (&o0.x)[g] = pk; else (&o1.x)[g - 4] = pk;
    }
    (void)op;
    *(uint4*)dst = o0;
    *(uint4*)(dst + 8) = o1;
}

// ---------------------------------------------------------------- pooling + final dot

__global__ __launch_bounds__(256) void pool_kernel(
    const float* __restrict__ x, const float* __restrict__ fcw,
    float* __restrict__ acc)
{
    __shared__ float red[4];
    const int chunk = blockIdx.x, b = blockIdx.y;
    const int t = threadIdx.x;
    float s = 0.f;
    for (int sr = 0; sr < 128; sr++) {
        const float* xr = x + ((size_t)(b * S_ + chunk * 128 + sr)) * D_;
#pragma unroll
        for (int i = 0; i < 3; i++) {
            int d = t + i * 256;
            s += xr[d] * fcw[d];
        }
    }
    float tot = block_reduce_sum(s, red);
    if (t == 0) atomicAdd(&acc[b], tot);
}

__global__ void final_kernel(const float* __restrict__ acc,
                             const float* __restrict__ fcb,
                             float* __restrict__ out)
{
    if (threadIdx.x < B_) out[threadIdx.x] = acc[threadIdx.x] * (1.f / S_) + fcb[0];
}

// ---------------------------------------------------------------- launch

extern "C" void kernel_launch(void* const* d_in, const int* in_sizes, int n_in,
                              void* d_out, int out_size, void* d_ws, size_t ws_size,
                              hipStream_t stream)
{
    (void)in_sizes; (void)n_in; (void)out_size; (void)ws_size;
    const int*   ids  = (const int*)d_in[0];
    const int*   rnd  = (const int*)d_in[1];
    const float* etok = (const float*)d_in[2];
    const float* epos = (const float*)d_in[3];
    const float* lng  = (const float*)d_in[4];
    const float* lnb  = (const float*)d_in[5];
    const float* Wq   = (const float*)d_in[6];
    const float* bq   = (const float*)d_in[7];
    const float* Wk   = (const float*)d_in[8];
    const float* bk   = (const float*)d_in[9];
    const float* Wv   = (const float*)d_in[10];
    const float* bv   = (const float*)d_in[11];
    const float* Wo   = (const float*)d_in[12];
    const float* bo   = (const float*)d_in[13];
    const float* ln1g = (const float*)d_in[14];
    const float* ln1b = (const float*)d_in[15];
    const float* W1   = (const float*)d_in[16];
    const float* b1   = (const float*)d_in[17];
    const float* W2   = (const float*)d_in[18];
    const float* b2   = (const float*)d_in[19];
    const float* ln2g = (const float*)d_in[20];
    const float* ln2b = (const float*)d_in[21];
    const float* fcw  = (const float*)d_in[22];
    const float* fcb  = (const float*)d_in[23];
    float* out = (float*)d_out;

    // ---- workspace layout (total ~148 MB) ----
    const size_t MD = (size_t)M_ * D_;                       // 6.29M elems
    const size_t PCTX = (size_t)2 * B_ * H_ * NCH_ * BLK_ * DH_;   // 1.573M
    const size_t PML  = (size_t)2 * B_ * H_ * NCH_ * BLK_;         // 24576

    float* x    = (float*)d_ws;            // MD f32
    float* regB = x + MD;                  // MD f32 (attn-out / ff-out)
    float* pctx = regB + MD;               // PCTX f32
    float* pm   = pctx + PCTX;             // PML f32
    float* pl   = pm + PML;                // PML f32
    u16*   qb   = (u16*)(pl + PML);        // MD bf16
    u16*   kb   = qb + MD;                 // MD bf16
    u16*   vb   = kb + MD;                 // MD bf16
    u16*   ctxb = vb + MD;                 // MD bf16
    u16*   ffhb = qb;                      // [M,FF] bf16 aliases q,k,v,ctxb (4*MD = M*FF exactly)
    u16*   xb   = ctxb + MD;               // MD bf16
    u16*   wb   = xb + MD;                 // 14.16M bf16 weights
    const size_t WSQ = (size_t)L_ * D_ * D_;      // 1.18M per proj weight set
    u16* wqb = wb;
    u16* wkb = wqb + WSQ;
    u16* wvb = wkb + WSQ;
    u16* wob = wvb + WSQ;
    u16* w1b = wob + WSQ;                  // [L][FF][D]
    u16* w2b = w1b + (size_t)L_ * FF_ * D_; // [L][D][FF]
    float* acc = (float*)(w2b + (size_t)L_ * D_ * FF_);

    hipMemsetAsync(acc, 0, 2 * sizeof(float), stream);

    // weight transpose-casts (fp32 [K,N] -> bf16 [N,K])
    for (int l = 0; l < L_; l++) {
        const size_t wo = (size_t)l * D_ * D_;
        tcast_kernel<<<dim3(D_ / 32, D_ / 32), 256, 0, stream>>>(Wq + wo, wqb + wo, D_, D_);
        tcast_kernel<<<dim3(D_ / 32, D_ / 32), 256, 0, stream>>>(Wk + wo, wkb + wo, D_, D_);
        tcast_kernel<<<dim3(D_ / 32, D_ / 32), 256, 0, stream>>>(Wv + wo, wvb + wo, D_, D_);
        tcast_kernel<<<dim3(D_ / 32, D_ / 32), 256, 0, stream>>>(Wo + wo, wob + wo, D_, D_);
        tcast_kernel<<<dim3(FF_ / 32, D_ / 32), 256, 0, stream>>>(
            W1 + (size_t)l * D_ * FF_, w1b + (size_t)l * FF_ * D_, D_, FF_);
        tcast_kernel<<<dim3(D_ / 32, FF_ / 32), 256, 0, stream>>>(
            W2 + (size_t)l * FF_ * D_, w2b + (size_t)l * D_ * FF_, FF_, D_);
    }

    embed_ln_kernel<<<M_, 256, 0, stream>>>(ids, etok, epos, lng, lnb, x, xb);

    dim3 gP(D_ / 128, M_ / 128);     // (6, 64)
    dim3 gF(FF_ / 128, M_ / 128);    // (24, 64)
    for (int l = 0; l < L_; l++) {
        const size_t wo = (size_t)l * D_ * D_;
        const size_t vo = (size_t)l * D_;
        gemm_bf16_kernel<0, 1><<<gP, 256, 0, stream>>>(xb, wqb + wo, bq + vo, qb, D_, D_);
        gemm_bf16_kernel<0, 1><<<gP, 256, 0, stream>>>(xb, wkb + wo, bk + vo, kb, D_, D_);
        gemm_bf16_kernel<0, 1><<<gP, 256, 0, stream>>>(xb, wvb + wo, bv + vo, vb, D_, D_);
        attn_sparse_kernel<<<dim3(NB_ - 2, H_, B_), 256, 0, stream>>>(qb, kb, vb, rnd, ctxb);
        attn_full_kernel<<<dim3(NCH_, H_, B_ * 2), 256, 0, stream>>>(qb, kb, vb, pctx, pm, pl);
        attn_combine_kernel<<<dim3(2, H_, B_), 256, 0, stream>>>(pctx, pm, pl, ctxb);
        gemm_bf16_kernel<0, 0><<<gP, 256, 0, stream>>>(ctxb, wob + wo, bo + vo, regB, D_, D_);
        add_ln_kernel<<<M_, 256, 0, stream>>>(x, regB, ln1g + vo, ln1b + vo, xb);
        gemm_bf16_kernel<1, 1><<<gF, 256, 0, stream>>>(
            xb, w1b + (size_t)l * FF_ * D_, b1 + (size_t)l * FF_, ffhb, FF_, D_);
        gemm_bf16_kernel<0, 0><<<gP, 256, 0, stream>>>(
            ffhb, w2b + (size_t)l * D_ * FF_, b2 + vo, regB, D_, FF_);
        add_ln_kernel<<<M_, 256, 0, stream>>>(x, regB, ln2g + vo, ln2b + vo, xb);
    }
    pool_kernel<<<dim3(S_ / 128, B_), 256, 0, stream>>>(x, fcw, acc);
    final_kernel<<<1, 64, 0, stream>>>(acc, fcb, out);
}

// Round 4
// 1075.230 us; speedup vs baseline: 5.2446x; 1.2636x over previous
//
#include <hip/hip_runtime.h>
#include <hip/hip_bf16.h>
#include <math.h>

// Problem constants (BigBird regressor, B=2, S=4096)
#define D_    768
#define H_    12
#define DH_   64
#define BLK_  64
#define L_    2
#define R_    3
#define B_    2
#define S_    4096
#define NB_   64          // S_/BLK_
#define M_    (B_*S_)     // 8192 tokens
#define FF_   (4*D_)      // 3072
#define NCH_  8           // split-K chunks for full-attention rows

#define VSTR  72          // Vt LDS row stride (u16): 144 B, 16B-aligned, 2-way banks
#define PSTR  72          // P  LDS row stride (u16)

typedef unsigned short u16;
typedef __bf16 bf16x8 __attribute__((ext_vector_type(8)));
typedef float  f32x4  __attribute__((ext_vector_type(4)));

// ---------------------------------------------------------------- helpers

__device__ inline float gelu_f(float x) {
    float x3 = x * x * x;
    return 0.5f * x * (1.f + tanhf(0.7978845608f * (x + 0.044715f * x3)));
}

__device__ inline float bf2f(u16 u) {
    unsigned v = ((unsigned)u) << 16;
    return __uint_as_float(v);
}

__device__ inline u16 f2bf(float f) {
    union { __hip_bfloat16 h; u16 u; } cv;
    cv.h = __float2bfloat16(f);
    return cv.u;
}

__device__ inline float block_reduce_sum(float v, float* red) {
#pragma unroll
    for (int o = 32; o > 0; o >>= 1) v += __shfl_xor(v, o, 64);
    int wv = threadIdx.x >> 6;
    if ((threadIdx.x & 63) == 0) red[wv] = v;
    __syncthreads();
    float tot = red[0] + red[1] + red[2] + red[3];
    __syncthreads();
    return tot;
}

// ---------------------------------------------------------------- weight transpose-cast: in fp32 [K,N] -> out bf16 [N,K]

__global__ __launch_bounds__(256) void tcast_kernel(
    const float* __restrict__ in, u16* __restrict__ out, int K, int N)
{
    __shared__ float tile[32][33];
    const int n0 = blockIdx.x * 32, k0 = blockIdx.y * 32;
    const int tx = threadIdx.x & 31, ty = threadIdx.x >> 5;
#pragma unroll
    for (int p = 0; p < 4; p++)
        tile[ty + p * 8][tx] = in[(size_t)(k0 + ty + p * 8) * N + n0 + tx];
    __syncthreads();
#pragma unroll
    for (int p = 0; p < 4; p++)
        out[(size_t)(n0 + ty + p * 8) * K + k0 + tx] = f2bf(tile[tx][ty + p * 8]);
}

// ---------------------------------------------------------------- embed+LN (writes fp32 x and bf16 xb)

__global__ __launch_bounds__(256) void embed_ln_kernel(
    const int* __restrict__ ids, const float* __restrict__ etok,
    const float* __restrict__ epos, const float* __restrict__ g,
    const float* __restrict__ bb, float* __restrict__ x, u16* __restrict__ xb)
{
    __shared__ float red[4];
    const int tok = blockIdx.x;
    const int s   = tok & (S_ - 1);
    const int id  = ids[tok];
    const int t   = threadIdx.x;
    float v[3];
    float sum = 0.f;
#pragma unroll
    for (int i = 0; i < 3; i++) {
        int d = t + i * 256;
        v[i] = etok[(size_t)id * D_ + d] + epos[(size_t)s * D_ + d];
        sum += v[i];
    }
    float mean = block_reduce_sum(sum, red) * (1.f / 768.f);
    float sq = 0.f;
#pragma unroll
    for (int i = 0; i < 3; i++) { float dd = v[i] - mean; sq += dd * dd; }
    float var = block_reduce_sum(sq, red) * (1.f / 768.f);
    float inv = rsqrtf(var + 1e-12f);
#pragma unroll
    for (int i = 0; i < 3; i++) {
        int d = t + i * 256;
        float o = (v[i] - mean) * inv * g[d] + bb[d];
        x[(size_t)tok * D_ + d] = o;
        xb[(size_t)tok * D_ + d] = f2bf(o);
    }
}

// ---------------------------------------------------------------- add + LN (in-place on x; also writes bf16 xb)

__global__ __launch_bounds__(256) void add_ln_kernel(
    float* __restrict__ x, const float* __restrict__ y,
    const float* __restrict__ g, const float* __restrict__ bb,
    u16* __restrict__ xb)
{
    __shared__ float red[4];
    const int tok = blockIdx.x;
    const int t   = threadIdx.x;
    float* xr = x + (size_t)tok * D_;
    const float* yr = y + (size_t)tok * D_;
    float v[3];
    float sum = 0.f;
#pragma unroll
    for (int i = 0; i < 3; i++) {
        int d = t + i * 256;
        v[i] = xr[d] + yr[d];
        sum += v[i];
    }
    float mean = block_reduce_sum(sum, red) * (1.f / 768.f);
    float sq = 0.f;
#pragma unroll
    for (int i = 0; i < 3; i++) { float dd = v[i] - mean; sq += dd * dd; }
    float var = block_reduce_sum(sq, red) * (1.f / 768.f);
    float inv = rsqrtf(var + 1e-12f);
#pragma unroll
    for (int i = 0; i < 3; i++) {
        int d = t + i * 256;
        float o = (v[i] - mean) * inv * g[d] + bb[d];
        xr[d] = o;
        xb[(size_t)tok * D_ + d] = f2bf(o);
    }
}

// ---------------------------------------------------------------- bf16 MFMA GEMM: C = A[M,K](bf16) @ Wt[N,K](bf16)^T + bias

template <int ACT, int OBF>
__global__ __launch_bounds__(256) void gemm_bf16_kernel(
    const u16* __restrict__ A, const u16* __restrict__ Wt,
    const float* __restrict__ bias, void* __restrict__ Cv,
    int N, int K)
{
    __shared__ __align__(16) u16 As[4096];   // 128x32 bf16, fragment-major
    __shared__ __align__(16) u16 Bs[4096];
    const int t = threadIdx.x;
    const int row0 = blockIdx.y * 128, col0 = blockIdx.x * 128;
    const int w = t >> 6, lane = t & 63;
    const int wr = w >> 1, wc = w & 1;
    const int i16 = lane & 15, qd = lane >> 4;

    const f32x4 zero = {0.f, 0.f, 0.f, 0.f};
    f32x4 acc[4][4];
#pragma unroll
    for (int r = 0; r < 4; r++)
#pragma unroll
        for (int c = 0; c < 4; c++) acc[r][c] = zero;

    const int e0 = t, e1 = t + 256;
    const int ra0 = e0 >> 2, ca0 = e0 & 3;
    const int ra1 = e1 >> 2, ca1 = e1 & 3;
    const int lds0 = ((ra0 >> 4) * 64 + ca0 * 16 + (ra0 & 15)) * 8;
    const int lds1 = ((ra1 >> 4) * 64 + ca1 * 16 + (ra1 & 15)) * 8;

    uint4 a0, a1, b0, b1;
    {
        a0 = *(const uint4*)(A + (size_t)(row0 + ra0) * K + ca0 * 8);
        a1 = *(const uint4*)(A + (size_t)(row0 + ra1) * K + ca1 * 8);
        b0 = *(const uint4*)(Wt + (size_t)(col0 + ra0) * K + ca0 * 8);
        b1 = *(const uint4*)(Wt + (size_t)(col0 + ra1) * K + ca1 * 8);
    }

    for (int k0 = 0; k0 < K; k0 += 32) {
        __syncthreads();
        *(uint4*)&As[lds0] = a0;
        *(uint4*)&As[lds1] = a1;
        *(uint4*)&Bs[lds0] = b0;
        *(uint4*)&Bs[lds1] = b1;
        __syncthreads();
        if (k0 + 32 < K) {
            int kn = k0 + 32;
            a0 = *(const uint4*)(A + (size_t)(row0 + ra0) * K + kn + ca0 * 8);
            a1 = *(const uint4*)(A + (size_t)(row0 + ra1) * K + kn + ca1 * 8);
            b0 = *(const uint4*)(Wt + (size_t)(col0 + ra0) * K + kn + ca0 * 8);
            b1 = *(const uint4*)(Wt + (size_t)(col0 + ra1) * K + kn + ca1 * 8);
        }
        bf16x8 af[4], bfr[4];
#pragma unroll
        for (int r = 0; r < 4; r++)
            af[r] = *(const bf16x8*)&As[(((wr * 4 + r) * 4 + qd) * 16 + i16) * 8];
#pragma unroll
        for (int c = 0; c < 4; c++)
            bfr[c] = *(const bf16x8*)&Bs[(((wc * 4 + c) * 4 + qd) * 16 + i16) * 8];
#pragma unroll
        for (int r = 0; r < 4; r++)
#pragma unroll
            for (int c = 0; c < 4; c++)
                acc[r][c] = __builtin_amdgcn_mfma_f32_16x16x32_bf16(af[r], bfr[c], acc[r][c], 0, 0, 0);
    }

#pragma unroll
    for (int c = 0; c < 4; c++) {
        int colg = col0 + wc * 64 + c * 16 + i16;
        float bsv = bias[colg];
#pragma unroll
        for (int r = 0; r < 4; r++) {
            int rowb = row0 + wr * 64 + r * 16 + qd * 4;
#pragma unroll
            for (int p = 0; p < 4; p++) {
                float val = acc[r][c][p] + bsv;
                if (ACT == 1) val = gelu_f(val);
                if (OBF == 1)
                    ((u16*)Cv)[(size_t)(rowb + p) * N + colg] = f2bf(val);
                else
                    ((float*)Cv)[(size_t)(rowb + p) * N + colg] = val;
            }
        }
    }
}

// ---------------------------------------------------------------- MFMA attention core
// 256 threads = 4 waves; wave w owns query rows w*16..w*16+15 of the 64-row block.
// Q/K in fragment-major LDS (conflict-free b128); V transposed Vt[d][VSTR];
// P crosses C/D->A layout via wave-private LDS slab (no barrier needed).

__device__ inline void attn_core(
    const u16* __restrict__ qtile,   // q + (b*S + qb*64)*D + h*64
    const u16* __restrict__ kbh,     // k + b*S*D + h*64
    const u16* __restrict__ vbh,     // v + b*S*D + h*64
    const int* kbl,                  // 8 key-block indices
    u16* Qs, u16* Ks, u16* Vt, u16* Ps,
    f32x4 (&o)[4], float (&m)[4], float (&l)[4])
{
    const int t = threadIdx.x;
    const int w = t >> 6, lane = t & 63;
    const int l15 = lane & 15, quad = lane >> 4;
    const int srow = lane;                 // staging row (0..63)
    const int skc0 = w, skc1 = w + 4;      // staging k-chunks (8 bf16 each)

    // ---- load Q + first K/V tiles into regs
    uint4 qr0 = *(const uint4*)(qtile + (size_t)srow * D_ + skc0 * 8);
    uint4 qr1 = *(const uint4*)(qtile + (size_t)srow * D_ + skc1 * 8);
    const u16* krow = kbh + (size_t)(kbl[0] * BLK_ + srow) * D_;
    const u16* vrow = vbh + (size_t)(kbl[0] * BLK_ + srow) * D_;
    uint4 kr0 = *(const uint4*)(krow + skc0 * 8);
    uint4 kr1 = *(const uint4*)(krow + skc1 * 8);
    uint4 vr0 = *(const uint4*)(vrow + skc0 * 8);
    uint4 vr1 = *(const uint4*)(vrow + skc1 * 8);

    const int sw0 = (((srow >> 4) * 8 + skc0) * 16 + (srow & 15)) * 8;
    const int sw1 = (((srow >> 4) * 8 + skc1) * 16 + (srow & 15)) * 8;

    *(uint4*)&Qs[sw0] = qr0;
    *(uint4*)&Qs[sw1] = qr1;
    *(uint4*)&Ks[sw0] = kr0;
    *(uint4*)&Ks[sw1] = kr1;
    {
        const u16* vs0 = (const u16*)&vr0;
        const u16* vs1 = (const u16*)&vr1;
#pragma unroll
        for (int j = 0; j < 8; j++) {
            Vt[(skc0 * 8 + j) * VSTR + srow] = vs0[j];
            Vt[(skc1 * 8 + j) * VSTR + srow] = vs1[j];
        }
    }
    __syncthreads();

    // hoisted Q A-fragments (this wave's 16 rows, k-halves 0/1)
    bf16x8 qf[2];
#pragma unroll
    for (int ki = 0; ki < 2; ki++)
        qf[ki] = *(const bf16x8*)&Qs[((w * 8 + ki * 4 + quad) * 16 + l15) * 8];

    const f32x4 zero = {0.f, 0.f, 0.f, 0.f};
#pragma unroll
    for (int c = 0; c < 4; c++) o[c] = zero;
#pragma unroll
    for (int r = 0; r < 4; r++) { m[r] = -1e30f; l[r] = 0.f; }

#pragma unroll
    for (int kbi = 0; kbi < 8; kbi++) {
        if (kbi + 1 < 8) {   // prefetch next K/V into regs
            const u16* kr = kbh + (size_t)(kbl[kbi + 1] * BLK_ + srow) * D_;
            const u16* vr = vbh + (size_t)(kbl[kbi + 1] * BLK_ + srow) * D_;
            kr0 = *(const uint4*)(kr + skc0 * 8);
            kr1 = *(const uint4*)(kr + skc1 * 8);
            vr0 = *(const uint4*)(vr + skc0 * 8);
            vr1 = *(const uint4*)(vr + skc1 * 8);
        }
        // ---- S = Q K^T  (C/D: row q = w*16+quad*4+r, col key = c*16+l15)
        f32x4 s[4];
#pragma unroll
        for (int c = 0; c < 4; c++) s[c] = zero;
#pragma unroll
        for (int ki = 0; ki < 2; ki++)
#pragma unroll
            for (int c = 0; c < 4; c++) {
                bf16x8 kf = *(const bf16x8*)&Ks[((c * 8 + ki * 4 + quad) * 16 + l15) * 8];
                s[c] = __builtin_amdgcn_mfma_f32_16x16x32_bf16(qf[ki], kf, s[c], 0, 0, 0);
            }
        // ---- register online softmax (row reduce: 4 in-lane + shfl over l15 bits)
        float pv[4][4];   // [c][r]
#pragma unroll
        for (int r = 0; r < 4; r++) {
            float s0 = s[0][r] * 0.125f, s1 = s[1][r] * 0.125f;
            float s2 = s[2][r] * 0.125f, s3 = s[3][r] * 0.125f;
            float lm = fmaxf(fmaxf(s0, s1), fmaxf(s2, s3));
            lm = fmaxf(lm, __shfl_xor(lm, 1, 16));
            lm = fmaxf(lm, __shfl_xor(lm, 2, 16));
            lm = fmaxf(lm, __shfl_xor(lm, 4, 16));
            lm = fmaxf(lm, __shfl_xor(lm, 8, 16));
            float mnew = fmaxf(m[r], lm);
            float al = __expf(m[r] - mnew);
            float p0 = __expf(s0 - mnew), p1 = __expf(s1 - mnew);
            float p2 = __expf(s2 - mnew), p3 = __expf(s3 - mnew);
            float ss = p0 + p1 + p2 + p3;
            ss += __shfl_xor(ss, 1, 16);
            ss += __shfl_xor(ss, 2, 16);
            ss += __shfl_xor(ss, 4, 16);
            ss += __shfl_xor(ss, 8, 16);
            l[r] = l[r] * al + ss;
            m[r] = mnew;
            o[0][r] *= al; o[1][r] *= al; o[2][r] *= al; o[3][r] *= al;
            pv[0][r] = p0; pv[1][r] = p1; pv[2][r] = p2; pv[3][r] = p3;
        }
        // ---- P: C/D layout -> LDS row-major [q][kk] (wave-private slab, quad-staggered)
#pragma unroll
        for (int cc = 0; cc < 4; cc++) {
            int c = (cc + quad) & 3;
#pragma unroll
            for (int r = 0; r < 4; r++)
                Ps[(w * 16 + quad * 4 + r) * PSTR + c * 16 + l15] = f2bf(pv[c][r]);
        }
        // ---- O += P V   (A = P rows w*16+l15, B = Vt)
#pragma unroll
        for (int ki = 0; ki < 2; ki++) {
            bf16x8 pf = *(const bf16x8*)&Ps[(w * 16 + l15) * PSTR + ki * 32 + quad * 8];
#pragma unroll
            for (int c = 0; c < 4; c++) {
                bf16x8 vf = *(const bf16x8*)&Vt[(c * 16 + l15) * VSTR + ki * 32 + quad * 8];
                o[c] = __builtin_amdgcn_mfma_f32_16x16x32_bf16(pf, vf, o[c], 0, 0, 0);
            }
        }
        // ---- stage next K/V
        if (kbi + 1 < 8) {
            __syncthreads();
            *(uint4*)&Ks[sw0] = kr0;
            *(uint4*)&Ks[sw1] = kr1;
            {
                const u16* vs0 = (const u16*)&vr0;
                const u16* vs1 = (const u16*)&vr1;
#pragma unroll
                for (int j = 0; j < 8; j++) {
                    Vt[(skc0 * 8 + j) * VSTR + srow] = vs0[j];
                    Vt[(skc1 * 8 + j) * VSTR + srow] = vs1[j];
                }
            }
            __syncthreads();
        }
    }
}

// ---------------------------------------------------------------- sparse attention (qblocks 1..62), bf16 out

__global__ __launch_bounds__(256) void attn_sparse_kernel(
    const u16* __restrict__ q, const u16* __restrict__ k,
    const u16* __restrict__ v, const int* __restrict__ rnd,
    u16* __restrict__ ctx)
{
    __shared__ __align__(16) u16 Qs[4096];
    __shared__ __align__(16) u16 Ks[4096];
    __shared__ __align__(16) u16 Vt[DH_ * VSTR];
    __shared__ __align__(16) u16 Ps[BLK_ * PSTR];

    const int ib = blockIdx.x + 1, h = blockIdx.y, b = blockIdx.z;
    const int t = threadIdx.x;
    const int w = t >> 6, lane = t & 63;
    const int l15 = lane & 15, quad = lane >> 4;

    const int* rp = rnd + ((size_t)(h * NB_ + ib)) * R_;
    int kbl[8] = {0, ib - 1, ib, ib + 1, NB_ - 1, rp[0], rp[1], rp[2]};

    const u16* qtile = q + ((size_t)(b * S_ + ib * BLK_)) * D_ + h * DH_;
    const u16* kbh   = k + ((size_t)b * S_) * D_ + h * DH_;
    const u16* vbh   = v + ((size_t)b * S_) * D_ + h * DH_;

    f32x4 o[4]; float m[4], l[4];
    attn_core(qtile, kbh, vbh, kbl, Qs, Ks, Vt, Ps, o, m, l);

#pragma unroll
    for (int r = 0; r < 4; r++) {
        int row = w * 16 + quad * 4 + r;
        float inv = 1.f / l[r];
#pragma unroll
        for (int c = 0; c < 4; c++)
            ctx[((size_t)(b * S_ + ib * BLK_ + row)) * D_ + h * DH_ + c * 16 + l15] =
                f2bf(o[c][r] * inv);
    }
}

// ---------------------------------------------------------------- full attention (qblocks 0,63) split-K partials

__global__ __launch_bounds__(256) void attn_full_kernel(
    const u16* __restrict__ q, const u16* __restrict__ k,
    const u16* __restrict__ v,
    float* __restrict__ pctx, float* __restrict__ pm, float* __restrict__ pl)
{
    __shared__ __align__(16) u16 Qs[4096];
    __shared__ __align__(16) u16 Ks[4096];
    __shared__ __align__(16) u16 Vt[DH_ * VSTR];
    __shared__ __align__(16) u16 Ps[BLK_ * PSTR];

    const int chunk = blockIdx.x, h = blockIdx.y;
    const int b = blockIdx.z >> 1, qsel = blockIdx.z & 1;
    const int qb = qsel ? (NB_ - 1) : 0;
    const int t = threadIdx.x;
    const int w = t >> 6, lane = t & 63;
    const int l15 = lane & 15, quad = lane >> 4;

    int kbl[8];
#pragma unroll
    for (int i = 0; i < 8; i++) kbl[i] = chunk * 8 + i;

    const u16* qtile = q + ((size_t)(b * S_ + qb * BLK_)) * D_ + h * DH_;
    const u16* kbh   = k + ((size_t)b * S_) * D_ + h * DH_;
    const u16* vbh   = v + ((size_t)b * S_) * D_ + h * DH_;

    f32x4 o[4]; float m[4], l[4];
    attn_core(qtile, kbh, vbh, kbl, Qs, Ks, Vt, Ps, o, m, l);

    const int ci = (((qsel * B_ + b) * H_ + h) * NCH_) + chunk;
#pragma unroll
    for (int r = 0; r < 4; r++) {
        int row = w * 16 + quad * 4 + r;
#pragma unroll
        for (int c = 0; c < 4; c++)
            pctx[((size_t)ci * BLK_ + row) * DH_ + c * 16 + l15] = o[c][r];
        if (l15 == 0) {
            pm[(size_t)ci * BLK_ + row] = m[r];
            pl[(size_t)ci * BLK_ + row] = l[r];
        }
    }
}

__global__ __launch_bounds__(256) void attn_combine_kernel(
    const float* __restrict__ pctx, const float* __restrict__ pm,
    const float* __restrict__ pl, u16* __restrict__ ctx)
{
    const int qsel = blockIdx.x, h = blockIdx.y, b = blockIdx.z;
    const int qb = qsel ? (NB_ - 1) : 0;
    const int t = threadIdx.x;
    const int row = t >> 2, q4 = t & 3;
    const int cbase = ((qsel * B_ + b) * H_ + h) * NCH_;

    float mv[NCH_], lv[NCH_];
    float M = -1e30f;
#pragma unroll
    for (int c = 0; c < NCH_; c++) {
        mv[c] = pm[(size_t)(cbase + c) * BLK_ + row];
        lv[c] = pl[(size_t)(cbase + c) * BLK_ + row];
        M = fmaxf(M, mv[c]);
    }
    float L = 0.f;
    float w[NCH_];
#pragma unroll
    for (int c = 0; c < NCH_; c++) { w[c] = __expf(mv[c] - M); L += lv[c] * w[c]; }
    float acc[16];
#pragma unroll
    for (int j = 0; j < 16; j++) acc[j] = 0.f;
#pragma unroll
    for (int c = 0; c < NCH_; c++) {
        const float* src = pctx + ((size_t)(cbase + c) * BLK_ + row) * DH_ + q4 * 16;
#pragma unroll
        for (int jj = 0; jj < 4; jj++) {
            float4 f = *(const float4*)(src + jj * 4);
            acc[jj * 4 + 0] = fmaf(f.x, w[c], acc[jj * 4 + 0]);
            acc[jj * 4 + 1] = fmaf(f.y, w[c], acc[jj * 4 + 1]);
            acc[jj * 4 + 2] = fmaf(f.z, w[c], acc[jj * 4 + 2]);
            acc[jj * 4 + 3] = fmaf(f.w, w[c], acc[jj * 4 + 3]);
        }
    }
    float invL = 1.f / L;
    u16* dst = ctx + ((size_t)(b * S_ + qb * BLK_ + row)) * D_ + h * DH_ + q4 * 16;
    uint4 o0, o1;
#pragma unroll
    for (int g = 0; g < 8; g++) {
        unsigned lo = (unsigned)f2bf(acc[g * 2 + 0] * invL);
        unsigned hi = (unsigned)f2bf(acc[g * 2 + 1] * invL);
        unsigned pk = lo | (hi << 16);
        if (g < 4) (&o0.x)[g] = pk; else (&o1.x)[g - 4] = pk;
    }
    *(uint4*)dst = o0;
    *(uint4*)(dst + 8) = o1;
}

// ---------------------------------------------------------------- pooling + final dot

__global__ __launch_bounds__(256) void pool_kernel(
    const float* __restrict__ x, const float* __restrict__ fcw,
    float* __restrict__ acc)
{
    __shared__ float red[4];
    const int chunk = blockIdx.x, b = blockIdx.y;
    const int t = threadIdx.x;
    float s = 0.f;
    for (int sr = 0; sr < 128; sr++) {
        const float* xr = x + ((size_t)(b * S_ + chunk * 128 + sr)) * D_;
#pragma unroll
        for (int i = 0; i < 3; i++) {
            int d = t + i * 256;
            s += xr[d] * fcw[d];
        }
    }
    float tot = block_reduce_sum(s, red);
    if (t == 0) atomicAdd(&acc[b], tot);
}

__global__ void final_kernel(const float* __restrict__ acc,
                             const float* __restrict__ fcb,
                             float* __restrict__ out)
{
    if (threadIdx.x < B_) out[threadIdx.x] = acc[threadIdx.x] * (1.f / S_) + fcb[0];
}

// ---------------------------------------------------------------- launch

extern "C" void kernel_launch(void* const* d_in, const int* in_sizes, int n_in,
                              void* d_out, int out_size, void* d_ws, size_t ws_size,
                              hipStream_t stream)
{
    (void)in_sizes; (void)n_in; (void)out_size; (void)ws_size;
    const int*   ids  = (const int*)d_in[0];
    const int*   rnd  = (const int*)d_in[1];
    const float* etok = (const float*)d_in[2];
    const float* epos = (const float*)d_in[3];
    const float* lng  = (const float*)d_in[4];
    const float* lnb  = (const float*)d_in[5];
    const float* Wq   = (const float*)d_in[6];
    const float* bq   = (const float*)d_in[7];
    const float* Wk   = (const float*)d_in[8];
    const float* bk   = (const float*)d_in[9];
    const float* Wv   = (const float*)d_in[10];
    const float* bv   = (const float*)d_in[11];
    const float* Wo   = (const float*)d_in[12];
    const float* bo   = (const float*)d_in[13];
    const float* ln1g = (const float*)d_in[14];
    const float* ln1b = (const float*)d_in[15];
    const float* W1   = (const float*)d_in[16];
    const float* b1   = (const float*)d_in[17];
    const float* W2   = (const float*)d_in[18];
    const float* b2   = (const float*)d_in[19];
    const float* ln2g = (const float*)d_in[20];
    const float* ln2b = (const float*)d_in[21];
    const float* fcw  = (const float*)d_in[22];
    const float* fcb  = (const float*)d_in[23];
    float* out = (float*)d_out;

    // ---- workspace layout (total ~148 MB) ----
    const size_t MD = (size_t)M_ * D_;
    const size_t PCTX = (size_t)2 * B_ * H_ * NCH_ * BLK_ * DH_;
    const size_t PML  = (size_t)2 * B_ * H_ * NCH_ * BLK_;

    float* x    = (float*)d_ws;            // MD f32
    float* regB = x + MD;                  // MD f32 (attn-out / ff-out)
    float* pctx = regB + MD;               // PCTX f32
    float* pm   = pctx + PCTX;             // PML f32
    float* pl   = pm + PML;                // PML f32
    u16*   qb   = (u16*)(pl + PML);        // MD bf16
    u16*   kb   = qb + MD;                 // MD bf16
    u16*   vb   = kb + MD;                 // MD bf16
    u16*   ctxb = vb + MD;                 // MD bf16
    u16*   ffhb = qb;                      // [M,FF] bf16 aliases q,k,v,ctxb
    u16*   xb   = ctxb + MD;               // MD bf16
    u16*   wb   = xb + MD;                 // bf16 weights
    const size_t WSQ = (size_t)L_ * D_ * D_;
    u16* wqb = wb;
    u16* wkb = wqb + WSQ;
    u16* wvb = wkb + WSQ;
    u16* wob = wvb + WSQ;
    u16* w1b = wob + WSQ;                   // [L][FF][D]
    u16* w2b = w1b + (size_t)L_ * FF_ * D_; // [L][D][FF]
    float* acc = (float*)(w2b + (size_t)L_ * D_ * FF_);

    hipMemsetAsync(acc, 0, 2 * sizeof(float), stream);

    for (int l = 0; l < L_; l++) {
        const size_t wo = (size_t)l * D_ * D_;
        tcast_kernel<<<dim3(D_ / 32, D_ / 32), 256, 0, stream>>>(Wq + wo, wqb + wo, D_, D_);
        tcast_kernel<<<dim3(D_ / 32, D_ / 32), 256, 0, stream>>>(Wk + wo, wkb + wo, D_, D_);
        tcast_kernel<<<dim3(D_ / 32, D_ / 32), 256, 0, stream>>>(Wv + wo, wvb + wo, D_, D_);
        tcast_kernel<<<dim3(D_ / 32, D_ / 32), 256, 0, stream>>>(Wo + wo, wob + wo, D_, D_);
        tcast_kernel<<<dim3(FF_ / 32, D_ / 32), 256, 0, stream>>>(
            W1 + (size_t)l * D_ * FF_, w1b + (size_t)l * FF_ * D_, D_, FF_);
        tcast_kernel<<<dim3(D_ / 32, FF_ / 32), 256, 0, stream>>>(
            W2 + (size_t)l * FF_ * D_, w2b + (size_t)l * D_ * FF_, FF_, D_);
    }

    embed_ln_kernel<<<M_, 256, 0, stream>>>(ids, etok, epos, lng, lnb, x, xb);

    dim3 gP(D_ / 128, M_ / 128);     // (6, 64)
    dim3 gF(FF_ / 128, M_ / 128);    // (24, 64)
    for (int l = 0; l < L_; l++) {
        const size_t wo = (size_t)l * D_ * D_;
        const size_t vo = (size_t)l * D_;
        gemm_bf16_kernel<0, 1><<<gP, 256, 0, stream>>>(xb, wqb + wo, bq + vo, qb, D_, D_);
        gemm_bf16_kernel<0, 1><<<gP, 256, 0, stream>>>(xb, wkb + wo, bk + vo, kb, D_, D_);
        gemm_bf16_kernel<0, 1><<<gP, 256, 0, stream>>>(xb, wvb + wo, bv + vo, vb, D_, D_);
        attn_sparse_kernel<<<dim3(NB_ - 2, H_, B_), 256, 0, stream>>>(qb, kb, vb, rnd, ctxb);
        attn_full_kernel<<<dim3(NCH_, H_, B_ * 2), 256, 0, stream>>>(qb, kb, vb, pctx, pm, pl);
        attn_combine_kernel<<<dim3(2, H_, B_), 256, 0, stream>>>(pctx, pm, pl, ctxb);
        gemm_bf16_kernel<0, 0><<<gP, 256, 0, stream>>>(ctxb, wob + wo, bo + vo, regB, D_, D_);
        add_ln_kernel<<<M_, 256, 0, stream>>>(x, regB, ln1g + vo, ln1b + vo, xb);
        gemm_bf16_kernel<1, 1><<<gF, 256, 0, stream>>>(
            xb, w1b + (size_t)l * FF_ * D_, b1 + (size_t)l * FF_, ffhb, FF_, D_);
        gemm_bf16_kernel<0, 0><<<gP, 256, 0, stream>>>(
            ffhb, w2b + (size_t)l * D_ * FF_, b2 + vo, regB, D_, FF_);
        add_ln_kernel<<<M_, 256, 0, stream>>>(x, regB, ln2g + vo, ln2b + vo, xb);
    }
    pool_kernel<<<dim3(S_ / 128, B_), 256, 0, stream>>>(x, fcw, acc);
    final_kernel<<<1, 64, 0, stream>>>(acc, fcb, out);
}